// Round 4
// baseline (1172.209 us; speedup 1.0000x reference)
//
#include <hip/hip_runtime.h>
#include <hip/hip_bf16.h>
#include <math.h>

#define N_TX   100000
#define N_USER 50000
#define F_TX   128
#define F_USER 64
#define HID    64
#define NH     4
#define OUTC   32
#define NE     500000
#define HC1    256          // NH*HID
#define SLOPE  0.2f

__device__ __forceinline__ float elu_f(float x) { return x > 0.f ? x : (expf(x) - 1.f); }
__device__ __forceinline__ float lrelu_exp(float x) { x = x > 0.f ? x : SLOPE * x; return expf(x); }

// diagonal-swizzled LDS index for the 256ch x 64node tile: conflict-free for
// (a) stage1 writes (lanes vary ch), (b) stage2 reads (lanes vary n),
// (c) conv2-stage reads (lanes vary n). Exactly 64 KiB.
__device__ __forceinline__ int sidx(int ch, int n) { return ch * 64 + ((n + ch) & 63); }

// ---------------- tiled fp32 GEMM: C = act(A[N,K] @ B[K,M] + bias) ----------------
__global__ __launch_bounds__(256) void gemm_kernel(const float* __restrict__ A,
    const float* __restrict__ B, const float* __restrict__ bias,
    float* __restrict__ C, int N, int K, int M, int act)
{
    __shared__ float As[16][65];
    __shared__ float Bs[16][65];
    const int tid = threadIdx.x;
    const int tx = tid % 16, ty = tid / 16;
    const int row0 = blockIdx.y * 64, col0 = blockIdx.x * 64;
    float acc[4][4] = {};
    for (int k0 = 0; k0 < K; k0 += 16) {
        #pragma unroll
        for (int i = 0; i < 4; ++i) {
            int idx = tid * 4 + i;           // 64x16 A tile
            int r = idx >> 4, kk = idx & 15;
            int gr = row0 + r;
            As[kk][r] = (gr < N) ? A[(size_t)gr * K + (k0 + kk)] : 0.f;
        }
        #pragma unroll
        for (int i = 0; i < 4; ++i) {
            int idx = tid * 4 + i;           // 16x64 B tile
            int kk = idx >> 6, c = idx & 63;
            int gc = col0 + c;
            Bs[kk][c] = (gc < M) ? B[(size_t)(k0 + kk) * M + gc] : 0.f;
        }
        __syncthreads();
        #pragma unroll
        for (int kk = 0; kk < 16; ++kk) {
            float a4[4], b4[4];
            #pragma unroll
            for (int i = 0; i < 4; ++i) a4[i] = As[kk][ty * 4 + i];
            #pragma unroll
            for (int j = 0; j < 4; ++j) b4[j] = Bs[kk][tx * 4 + j];
            #pragma unroll
            for (int i = 0; i < 4; ++i)
                #pragma unroll
                for (int j = 0; j < 4; ++j) acc[i][j] += a4[i] * b4[j];
        }
        __syncthreads();
    }
    #pragma unroll
    for (int i = 0; i < 4; ++i) {
        int r = row0 + ty * 4 + i;
        if (r >= N) continue;
        #pragma unroll
        for (int j = 0; j < 4; ++j) {
            int c = col0 + tx * 4 + j;
            if (c >= M) continue;
            float v = acc[i][j] + (bias ? bias[c] : 0.f);
            if (act == 1) v = elu_f(v);
            C[(size_t)r * M + c] = v;
        }
    }
}

// ------------- fold attention vectors into weights: Mv[k,h] = sum_c W[k,h*C+c]*a[h,c] -------------
struct AVArgs  { const float* W; const float* a; float* out; int K; int H; int C; };
struct AVArgs6 { AVArgs t[6]; };

__global__ void attn_vecs_kernel(AVArgs6 args)
{
    AVArgs A = args.t[blockIdx.x];
    int tid = threadIdx.x;
    if (tid < A.K * A.H) {
        int k = tid % A.K, h = tid / A.K;
        float s = 0.f;
        const float* wrow = A.W + (size_t)k * (A.H * A.C) + h * A.C;
        const float* arow = A.a + h * A.C;
        for (int c = 0; c < A.C; ++c) s += wrow[c] * arow[c];
        A.out[k * A.H + h] = s;
    }
}

// ------------- per-node attention scalars, K=64, H=4 -------------
__global__ void node_attn4(const float* __restrict__ X, const float* __restrict__ Mv,
                           float* __restrict__ out, int N)
{
    int wave = blockIdx.x * (blockDim.x >> 6) + (threadIdx.x >> 6);
    int lane = threadIdx.x & 63;
    if (wave >= N) return;
    float x = X[(size_t)wave * 64 + lane];
    float p0 = x * Mv[lane * 4 + 0];
    float p1 = x * Mv[lane * 4 + 1];
    float p2 = x * Mv[lane * 4 + 2];
    float p3 = x * Mv[lane * 4 + 3];
    for (int off = 32; off > 0; off >>= 1) {
        p0 += __shfl_down(p0, off);
        p1 += __shfl_down(p1, off);
        p2 += __shfl_down(p2, off);
        p3 += __shfl_down(p3, off);
    }
    if (lane == 0) {
        float* o = out + (size_t)wave * 4;
        o[0] = p0; o[1] = p1; o[2] = p2; o[3] = p3;
    }
}

// ================= CSR build =================
__global__ __launch_bounds__(256) void hist_kernel(const int* __restrict__ dst,
    int* __restrict__ deg, int E)
{
    int e = blockIdx.x * 256 + threadIdx.x;
    if (e < E) atomicAdd(&deg[dst[e]], 1);
}

__global__ __launch_bounds__(256) void block_sum_kernel(const int* __restrict__ deg,
    int* __restrict__ bsum, int Nd)
{
    __shared__ int lds[256];
    int t = threadIdx.x;
    int i = blockIdx.x * 256 + t;
    lds[t] = (i < Nd) ? deg[i] : 0;
    __syncthreads();
    for (int o = 128; o > 0; o >>= 1) {
        if (t < o) lds[t] += lds[t + o];
        __syncthreads();
    }
    if (t == 0) bsum[blockIdx.x] = lds[0];
}

__global__ __launch_bounds__(512) void scan_bsum_kernel(int* __restrict__ bsum, int nb)
{
    __shared__ int lds[512];
    int t = threadIdx.x;
    int v = (t < nb) ? bsum[t] : 0;
    lds[t] = v;
    __syncthreads();
    for (int o = 1; o < 512; o <<= 1) {
        int x = (t >= o) ? lds[t - o] : 0;
        __syncthreads();
        lds[t] += x;
        __syncthreads();
    }
    if (t < nb) bsum[t] = lds[t] - v;   // exclusive
}

__global__ __launch_bounds__(256) void scan_final_kernel(const int* __restrict__ deg,
    const int* __restrict__ bsum_excl, int* __restrict__ rowptr, int* __restrict__ cursor,
    int Nd, int E)
{
    __shared__ int lds[256];
    int t = threadIdx.x;
    int i = blockIdx.x * 256 + t;
    int v = (i < Nd) ? deg[i] : 0;
    lds[t] = v;
    __syncthreads();
    for (int o = 1; o < 256; o <<= 1) {
        int x = (t >= o) ? lds[t - o] : 0;
        __syncthreads();
        lds[t] += x;
        __syncthreads();
    }
    int excl = lds[t] - v + bsum_excl[blockIdx.x];
    if (i < Nd) {
        rowptr[i] = excl;
        cursor[i] = excl;
        if (i == Nd - 1) rowptr[Nd] = E;
    }
}

__global__ __launch_bounds__(256) void scatter_kernel(const int* __restrict__ src,
    const int* __restrict__ dst, int* __restrict__ cursor, int* __restrict__ csr, int E)
{
    int e = blockIdx.x * 256 + threadIdx.x;
    if (e < E) {
        int p = atomicAdd(&cursor[dst[e]], 1);
        csr[p] = src[e];
    }
}

// ---------- shared stage-1: aggregate 16 nodes/wave into the swizzled LDS tile ----------
__device__ __forceinline__ void acc_edge(int s, int lane,
    const float* __restrict__ als, const float* __restrict__ hsrc, const float4& A,
    float& a0, float& a1, float& a2, float& a3,
    float& w0, float& w1, float& w2, float& w3)
{
    float4 v = *(const float4*)(als + (size_t)s * 4);
    float x = hsrc[(size_t)s * 64 + lane];
    float e0 = lrelu_exp(v.x + A.x);
    float e1 = lrelu_exp(v.y + A.y);
    float e2 = lrelu_exp(v.z + A.z);
    float e3 = lrelu_exp(v.w + A.w);
    a0 = fmaf(e0, x, a0); w0 += e0;
    a1 = fmaf(e1, x, a1); w1 += e1;
    a2 = fmaf(e2, x, a2); w2 += e2;
    a3 = fmaf(e3, x, a3); w3 += e3;
}

__device__ __forceinline__ void stage1_agg(const int* __restrict__ rowptr,
    const int* __restrict__ csr, const float* __restrict__ hsrc,
    const float* __restrict__ als, const float* __restrict__ ald,
    float* sT, int base, int Nd, int w, int lane)
{
    for (int nn = 0; nn < 16; ++nn) {
        int nl = w * 16 + nn;
        int d = base + nl;
        if (d >= Nd) continue;
        int beg = rowptr[d], end = rowptr[d + 1];
        float4 A = *(const float4*)(ald + (size_t)d * 4);
        float a0 = 0.f, a1 = 0.f, a2 = 0.f, a3 = 0.f;
        float w0 = 0.f, w1 = 0.f, w2 = 0.f, w3 = 0.f;
        int i = beg;
        for (; i + 2 <= end; i += 2) {
            acc_edge(csr[i],     lane, als, hsrc, A, a0, a1, a2, a3, w0, w1, w2, w3);
            acc_edge(csr[i + 1], lane, als, hsrc, A, a0, a1, a2, a3, w0, w1, w2, w3);
        }
        if (i < end)
            acc_edge(csr[i], lane, als, hsrc, A, a0, a1, a2, a3, w0, w1, w2, w3);
        sT[sidx(lane,       nl)] = a0 / (w0 + 1e-16f);
        sT[sidx(64 + lane,  nl)] = a1 / (w1 + 1e-16f);
        sT[sidx(128 + lane, nl)] = a2 / (w2 + 1e-16f);
        sT[sidx(192 + lane, nl)] = a3 / (w3 + 1e-16f);
    }
}

// ================= conv1 u2t fused: aggregate + per-head transform + elu + dot =================
// output: ald2[d] = sum_h elu(t1_row_h) . vvec_h   (t1 never hits memory)
__global__ __launch_bounds__(256, 2) void conv1_fused_u2t(
    const int* __restrict__ rowptr, const int* __restrict__ csr,
    const float* __restrict__ hsrc, const float* __restrict__ als,
    const float* __restrict__ ald, const float* __restrict__ W1,
    const float* __restrict__ b1, const float* __restrict__ vvec,
    float* __restrict__ dot_out, int Nd)
{
    __shared__ float sT[256 * 64];      // 64 KiB, diagonal-swizzled
    const int tid = threadIdx.x;
    const int lane = tid & 63;
    const int w = tid >> 6;
    const int base = blockIdx.x * 64;

    stage1_agg(rowptr, csr, hsrc, als, ald, sT, base, Nd, w, lane);
    __syncthreads();

    // stage 2: thread -> (node = lane, head = w); W1 rows wave-uniform (SGPR FMAs)
    const int h = w, nl = lane;
    float acc[64];
    const float* brow = b1 + h * 64;
    #pragma unroll
    for (int j = 0; j < 64; ++j) acc[j] = brow[j];
    #pragma unroll 1
    for (int c = 0; c < 64; ++c) {
        float xc = sT[sidx(h * 64 + c, nl)];
        const float* wrow = W1 + (size_t)c * 256 + h * 64;
        #pragma unroll
        for (int j = 0; j < 64; ++j) acc[j] = fmaf(xc, wrow[j], acc[j]);
    }
    float dsum = 0.f;
    const float* vrow = vvec + h * 64;
    #pragma unroll
    for (int j = 0; j < 64; ++j) {
        float v = acc[j];
        v = v > 0.f ? v : (expf(v) - 1.f);
        dsum += v * vrow[j];
    }
    __syncthreads();                    // all sT reads done; safe to alias for reduction
    sT[h * 64 + nl] = dsum;
    __syncthreads();
    if (tid < 64 && base + tid < Nd)
        dot_out[base + tid] = sT[tid] + sT[64 + tid] + sT[128 + tid] + sT[192 + tid];
}

// ================= conv1 t2u fused: aggregate + transform + elu (u1 in LDS) + conv2 proj ========
// outputs: hs2[d,0:32] = u1_row @ W2 ;  als2[d] = hs2_row . as2   (u1 never hits memory)
__global__ __launch_bounds__(256, 2) void conv1_fused_t2u(
    const int* __restrict__ rowptr, const int* __restrict__ csr,
    const float* __restrict__ hsrc, const float* __restrict__ als,
    const float* __restrict__ ald, const float* __restrict__ W1,
    const float* __restrict__ b1, const float* __restrict__ W2,
    const float* __restrict__ as2,
    float* __restrict__ hs2, float* __restrict__ als2, int Nd)
{
    __shared__ float sT[256 * 64];
    const int tid = threadIdx.x;
    const int lane = tid & 63;
    const int w = tid >> 6;
    const int base = blockIdx.x * 64;

    stage1_agg(rowptr, csr, hsrc, als, ald, sT, base, Nd, w, lane);
    __syncthreads();

    // stage 2: per-head transform, elu, write u1 slice back in place (own cells only)
    const int h = w, nl = lane;
    {
        float acc[64];
        const float* brow = b1 + h * 64;
        #pragma unroll
        for (int j = 0; j < 64; ++j) acc[j] = brow[j];
        #pragma unroll 1
        for (int c = 0; c < 64; ++c) {
            float xc = sT[sidx(h * 64 + c, nl)];
            const float* wrow = W1 + (size_t)c * 256 + h * 64;
            #pragma unroll
            for (int j = 0; j < 64; ++j) acc[j] = fmaf(xc, wrow[j], acc[j]);
        }
        // cells (h*64+j, nl) are read/written only by this thread -> no barrier needed
        #pragma unroll
        for (int j = 0; j < 64; ++j) {
            float v = acc[j];
            sT[sidx(h * 64 + j, nl)] = v > 0.f ? v : (expf(v) - 1.f);
        }
    }
    __syncthreads();

    // stage 3: hs2 = u1 @ W2 (thread -> node = lane, col-group = w), als2 = hs2 . as2
    float o8[8] = {0.f, 0.f, 0.f, 0.f, 0.f, 0.f, 0.f, 0.f};
    #pragma unroll 1
    for (int k = 0; k < 256; ++k) {
        float x = sT[sidx(k, nl)];
        const float* w2r = W2 + (size_t)k * 32 + w * 8;   // wave-uniform row
        #pragma unroll
        for (int m = 0; m < 8; ++m) o8[m] = fmaf(x, w2r[m], o8[m]);
    }
    const int d = base + nl;
    float p = 0.f;
    #pragma unroll
    for (int m = 0; m < 8; ++m) p += o8[m] * as2[w * 8 + m];
    if (d < Nd) {
        float4 oa = make_float4(o8[0], o8[1], o8[2], o8[3]);
        float4 ob = make_float4(o8[4], o8[5], o8[6], o8[7]);
        *(float4*)(hs2 + (size_t)d * 32 + w * 8)     = oa;
        *(float4*)(hs2 + (size_t)d * 32 + w * 8 + 4) = ob;
    }
    __syncthreads();                    // stage-3 reads done; alias sT for reduction
    sT[w * 64 + nl] = p;
    __syncthreads();
    if (tid < 64 && base + tid < Nd)
        als2[base + tid] = sT[tid] + sT[64 + tid] + sT[128 + tid] + sT[192 + tid];
}

// ================= conv2: fused edge-softmax + aggregation + bias/ELU + classifier ==========
__global__ __launch_bounds__(256) void conv2_fused_kernel(const int* __restrict__ rowptr,
    const int* __restrict__ csr, const float* __restrict__ hs2,
    const float* __restrict__ als2, const float* __restrict__ ald2,
    const float* __restrict__ b2, const float* __restrict__ Wc, const float* __restrict__ bc,
    float* __restrict__ out, int Nd)
{
    int d = blockIdx.x * 4 + (threadIdx.x >> 6);
    int lane = threadIdx.x & 63;
    if (d >= Nd) return;
    int beg = rowptr[d], end = rowptr[d + 1];
    float aldd = ald2[d];
    int half = lane >> 5, c = lane & 31;
    float acc = 0.f, wsum = 0.f;
    for (int i = beg + half; i < end; i += 2) {
        int s = csr[i];
        float w = lrelu_exp(als2[s] + aldd);
        acc = fmaf(w, hs2[(size_t)s * 32 + c], acc);
        wsum += w;
    }
    acc  += __shfl_down(acc, 32);
    wsum += __shfl_down(wsum, 32);
    float val = 0.f;
    if (lane < 32) {
        float t2 = acc / (wsum + 1e-16f) + b2[c];
        t2 = t2 > 0.f ? t2 : (expf(t2) - 1.f);
        val = t2 * Wc[c];
    }
    #pragma unroll
    for (int o = 16; o > 0; o >>= 1) val += __shfl_down(val, o);
    if (lane == 0) out[d] = val + bc[0];
}

extern "C" void kernel_launch(void* const* d_in, const int* in_sizes, int n_in,
                              void* d_out, int out_size, void* d_ws, size_t ws_size,
                              hipStream_t stream)
{
    const float* x_tx    = (const float*)d_in[0];
    const float* x_user  = (const float*)d_in[1];
    const int*   ei_u2t  = (const int*)d_in[2];
    const int*   ei_t2u  = (const int*)d_in[3];
    const float* Wp_tx   = (const float*)d_in[4];
    const float* bp_tx   = (const float*)d_in[5];
    const float* Wp_user = (const float*)d_in[6];
    const float* bp_user = (const float*)d_in[7];
    const float* W1_u2t  = (const float*)d_in[8];
    const float* as1_u2t = (const float*)d_in[9];
    const float* ad1_u2t = (const float*)d_in[10];
    const float* b1_u2t  = (const float*)d_in[11];
    const float* W2_u2t  = (const float*)d_in[12];
    const float* as2_u2t = (const float*)d_in[13];
    const float* ad2_u2t = (const float*)d_in[14];
    const float* b2_u2t  = (const float*)d_in[15];
    const float* W1_t2u  = (const float*)d_in[16];
    const float* as1_t2u = (const float*)d_in[17];
    const float* ad1_t2u = (const float*)d_in[18];
    const float* b1_t2u  = (const float*)d_in[19];
    const float* Wc      = (const float*)d_in[24];
    const float* bc      = (const float*)d_in[25];
    float* out = (float*)d_out;
    float* ws  = (float*)d_ws;

    const int* src_u2t = ei_u2t;            // user ids
    const int* dst_u2t = ei_u2t + NE;       // tx ids
    const int* src_t2u = ei_t2u;            // tx ids
    const int* dst_u   = ei_t2u + NE;       // user ids

    // ---- workspace layout (floats); total ~13.6M floats = 54.4 MB ----
    float* h_tx  = ws;                      //  6,400,000
    float* h_us  = ws + 6400000;            //  3,200,000
    float* hs2   = ws + 9600000;            //  1,600,000
    float* als2  = ws + 11200000;           //     50,000
    float* ald2  = ws + 11250000;           //    100,000
    float* als_s = ws + 11350000;           //    400,000  (sized for N_TX)
    float* ald_d = ws + 11750000;           //    400,000
    float* avec  = ws + 12150000;           //      1,536
    // ---- int region ----
    int* ibase    = (int*)(ws + 12152000);
    int* deg_t    = ibase;                  //   100,000  (deg_t+deg_u contiguous -> one memset)
    int* deg_u    = ibase + 100000;         //    50,000
    int* rowptr_t = ibase + 150000;         //   100,001
    int* cur_t    = ibase + 250001;         //   100,000
    int* csr_t    = ibase + 350001;         //   500,000
    int* rowptr_u = ibase + 850001;         //    50,001
    int* cur_u    = ibase + 900002;         //    50,000
    int* csr_u    = ibase + 950002;         //   500,000
    int* bsum_t   = ibase + 1450002;        //       512
    int* bsum_u   = ibase + 1450514;        //       512

    float* Msrc_u2t = avec + 0;
    float* Mdst_u2t = avec + 256;
    float* Msrc_t2u = avec + 512;
    float* Mdst_t2u = avec + 768;
    float* vsrc2    = avec + 1024;          // unused now (als2 computed from hs2.as2)
    float* vdst2    = avec + 1280;

    const int NB_T = (N_TX + 255) / 256;    // 391
    const int NB_U = (N_USER + 255) / 256;  // 196

    // ---- fold attention vectors into weights ----
    AVArgs6 av;
    av.t[0] = { W1_u2t, as1_u2t, Msrc_u2t, HID, NH, HID };
    av.t[1] = { W1_u2t, ad1_u2t, Mdst_u2t, HID, NH, HID };
    av.t[2] = { W1_t2u, as1_t2u, Msrc_t2u, HID, NH, HID };
    av.t[3] = { W1_t2u, ad1_t2u, Mdst_t2u, HID, NH, HID };
    av.t[4] = { W2_u2t, as2_u2t, vsrc2, HC1, 1, OUTC };
    av.t[5] = { W2_u2t, ad2_u2t, vdst2, HC1, 1, OUTC };
    attn_vecs_kernel<<<6, 256, 0, stream>>>(av);

    // ---- zero degree histograms (only remaining memset) ----
    hipMemsetAsync(deg_t, 0, 150000 * sizeof(int), stream);

    // ---- CSR build for u2t (dst = tx) ----
    hist_kernel<<<(NE + 255) / 256, 256, 0, stream>>>(dst_u2t, deg_t, NE);
    block_sum_kernel<<<NB_T, 256, 0, stream>>>(deg_t, bsum_t, N_TX);
    scan_bsum_kernel<<<1, 512, 0, stream>>>(bsum_t, NB_T);
    scan_final_kernel<<<NB_T, 256, 0, stream>>>(deg_t, bsum_t, rowptr_t, cur_t, N_TX, NE);
    scatter_kernel<<<(NE + 255) / 256, 256, 0, stream>>>(src_u2t, dst_u2t, cur_t, csr_t, NE);

    // ---- CSR build for t2u (dst = user) ----
    hist_kernel<<<(NE + 255) / 256, 256, 0, stream>>>(dst_u, deg_u, NE);
    block_sum_kernel<<<NB_U, 256, 0, stream>>>(deg_u, bsum_u, N_USER);
    scan_bsum_kernel<<<1, 512, 0, stream>>>(bsum_u, NB_U);
    scan_final_kernel<<<NB_U, 256, 0, stream>>>(deg_u, bsum_u, rowptr_u, cur_u, N_USER, NE);
    scatter_kernel<<<(NE + 255) / 256, 256, 0, stream>>>(src_t2u, dst_u, cur_u, csr_u, NE);

    // ---- input projections ----
    gemm_kernel<<<dim3(1, (N_TX + 63) / 64), 256, 0, stream>>>(
        x_tx, Wp_tx, bp_tx, h_tx, N_TX, F_TX, HID, 1);
    gemm_kernel<<<dim3(1, (N_USER + 63) / 64), 256, 0, stream>>>(
        x_user, Wp_user, bp_user, h_us, N_USER, F_USER, HID, 1);

    // ================= conv1, u2t (dst = tx): only ald2 leaves the kernel ==========
    node_attn4<<<(N_USER + 3) / 4, 256, 0, stream>>>(h_us, Msrc_u2t, als_s, N_USER);
    node_attn4<<<(N_TX   + 3) / 4, 256, 0, stream>>>(h_tx, Mdst_u2t, ald_d, N_TX);
    conv1_fused_u2t<<<(N_TX + 63) / 64, 256, 0, stream>>>(
        rowptr_t, csr_t, h_us, als_s, ald_d, W1_u2t, b1_u2t, vdst2, ald2, N_TX);

    // ================= conv1, t2u (dst = user): emits hs2 + als2 directly ==========
    node_attn4<<<(N_TX   + 3) / 4, 256, 0, stream>>>(h_tx, Msrc_t2u, als_s, N_TX);
    node_attn4<<<(N_USER + 3) / 4, 256, 0, stream>>>(h_us, Mdst_t2u, ald_d, N_USER);
    conv1_fused_t2u<<<(N_USER + 63) / 64, 256, 0, stream>>>(
        rowptr_u, csr_u, h_tx, als_s, ald_d, W1_t2u, b1_t2u, W2_u2t, as2_u2t,
        hs2, als2, N_USER);

    // ================= conv2 + classifier =================
    conv2_fused_kernel<<<(N_TX + 3) / 4, 256, 0, stream>>>(
        rowptr_t, csr_t, hs2, als2, ald2, b2_u2t, Wc, bc, out, N_TX);
}

// Round 5
// 1066.728 us; speedup vs baseline: 1.0989x; 1.0989x over previous
//
#include <hip/hip_runtime.h>
#include <hip/hip_bf16.h>
#include <math.h>

#define N_TX   100000
#define N_USER 50000
#define F_TX   128
#define F_USER 64
#define HID    64
#define NH     4
#define OUTC   32
#define NE     500000
#define HC1    256          // NH*HID
#define SLOPE  0.2f

__device__ __forceinline__ float elu_f(float x) { return x > 0.f ? x : (expf(x) - 1.f); }
__device__ __forceinline__ float lrelu_exp(float x) { x = x > 0.f ? x : SLOPE * x; return expf(x); }

// diagonal-swizzled LDS index for the 256ch x 64node tile.
// staging writes (lanes vary ch), stage-2 reads (lanes vary n): both 2-way = free.
__device__ __forceinline__ int sidx(int ch, int n) { return ch * 64 + ((n + ch) & 63); }

// ---------------- tiled fp32 GEMM: C = act(A[N,K] @ B[K,M] + bias) ----------------
__global__ __launch_bounds__(256) void gemm_kernel(const float* __restrict__ A,
    const float* __restrict__ B, const float* __restrict__ bias,
    float* __restrict__ C, int N, int K, int M, int act)
{
    __shared__ float As[16][65];
    __shared__ float Bs[16][65];
    const int tid = threadIdx.x;
    const int tx = tid % 16, ty = tid / 16;
    const int row0 = blockIdx.y * 64, col0 = blockIdx.x * 64;
    float acc[4][4] = {};
    for (int k0 = 0; k0 < K; k0 += 16) {
        #pragma unroll
        for (int i = 0; i < 4; ++i) {
            int idx = tid * 4 + i;           // 64x16 A tile
            int r = idx >> 4, kk = idx & 15;
            int gr = row0 + r;
            As[kk][r] = (gr < N) ? A[(size_t)gr * K + (k0 + kk)] : 0.f;
        }
        #pragma unroll
        for (int i = 0; i < 4; ++i) {
            int idx = tid * 4 + i;           // 16x64 B tile
            int kk = idx >> 6, c = idx & 63;
            int gc = col0 + c;
            Bs[kk][c] = (gc < M) ? B[(size_t)(k0 + kk) * M + gc] : 0.f;
        }
        __syncthreads();
        #pragma unroll
        for (int kk = 0; kk < 16; ++kk) {
            float a4[4], b4[4];
            #pragma unroll
            for (int i = 0; i < 4; ++i) a4[i] = As[kk][ty * 4 + i];
            #pragma unroll
            for (int j = 0; j < 4; ++j) b4[j] = Bs[kk][tx * 4 + j];
            #pragma unroll
            for (int i = 0; i < 4; ++i)
                #pragma unroll
                for (int j = 0; j < 4; ++j) acc[i][j] += a4[i] * b4[j];
        }
        __syncthreads();
    }
    #pragma unroll
    for (int i = 0; i < 4; ++i) {
        int r = row0 + ty * 4 + i;
        if (r >= N) continue;
        #pragma unroll
        for (int j = 0; j < 4; ++j) {
            int c = col0 + tx * 4 + j;
            if (c >= M) continue;
            float v = acc[i][j] + (bias ? bias[c] : 0.f);
            if (act == 1) v = elu_f(v);
            C[(size_t)r * M + c] = v;
        }
    }
}

// ------------- fold attention vectors into weights: Mv[k,h] = sum_c W[k,h*C+c]*a[h,c] -------------
struct AVArgs  { const float* W; const float* a; float* out; int K; int H; int C; };
struct AVArgs6 { AVArgs t[6]; };

__global__ void attn_vecs_kernel(AVArgs6 args)
{
    AVArgs A = args.t[blockIdx.x];
    int tid = threadIdx.x;
    if (tid < A.K * A.H) {
        int k = tid % A.K, h = tid / A.K;
        float s = 0.f;
        const float* wrow = A.W + (size_t)k * (A.H * A.C) + h * A.C;
        const float* arow = A.a + h * A.C;
        for (int c = 0; c < A.C; ++c) s += wrow[c] * arow[c];
        A.out[k * A.H + h] = s;
    }
}

// ------------- per-node attention scalars, K=64, two head-quads in one pass -------------
__global__ void node_attn8(const float* __restrict__ X, const float* __restrict__ Mva,
    const float* __restrict__ Mvb, float* __restrict__ outa, float* __restrict__ outb, int N)
{
    int wave = blockIdx.x * (blockDim.x >> 6) + (threadIdx.x >> 6);
    int lane = threadIdx.x & 63;
    if (wave >= N) return;
    float x = X[(size_t)wave * 64 + lane];
    float a0 = x * Mva[lane * 4 + 0];
    float a1 = x * Mva[lane * 4 + 1];
    float a2 = x * Mva[lane * 4 + 2];
    float a3 = x * Mva[lane * 4 + 3];
    float b0 = x * Mvb[lane * 4 + 0];
    float b1 = x * Mvb[lane * 4 + 1];
    float b2 = x * Mvb[lane * 4 + 2];
    float b3 = x * Mvb[lane * 4 + 3];
    for (int off = 32; off > 0; off >>= 1) {
        a0 += __shfl_down(a0, off); a1 += __shfl_down(a1, off);
        a2 += __shfl_down(a2, off); a3 += __shfl_down(a3, off);
        b0 += __shfl_down(b0, off); b1 += __shfl_down(b1, off);
        b2 += __shfl_down(b2, off); b3 += __shfl_down(b3, off);
    }
    if (lane == 0) {
        float* oa = outa + (size_t)wave * 4;
        oa[0] = a0; oa[1] = a1; oa[2] = a2; oa[3] = a3;
        float* ob = outb + (size_t)wave * 4;
        ob[0] = b0; ob[1] = b1; ob[2] = b2; ob[3] = b3;
    }
}

// ================= CSR build =================
__global__ __launch_bounds__(256) void hist_kernel(const int* __restrict__ dst,
    int* __restrict__ deg, int E)
{
    int e = blockIdx.x * 256 + threadIdx.x;
    if (e < E) atomicAdd(&deg[dst[e]], 1);
}

__global__ __launch_bounds__(256) void block_sum_kernel(const int* __restrict__ deg,
    int* __restrict__ bsum, int Nd)
{
    __shared__ int lds[256];
    int t = threadIdx.x;
    int i = blockIdx.x * 256 + t;
    lds[t] = (i < Nd) ? deg[i] : 0;
    __syncthreads();
    for (int o = 128; o > 0; o >>= 1) {
        if (t < o) lds[t] += lds[t + o];
        __syncthreads();
    }
    if (t == 0) bsum[blockIdx.x] = lds[0];
}

__global__ __launch_bounds__(512) void scan_bsum_kernel(int* __restrict__ bsum, int nb)
{
    __shared__ int lds[512];
    int t = threadIdx.x;
    int v = (t < nb) ? bsum[t] : 0;
    lds[t] = v;
    __syncthreads();
    for (int o = 1; o < 512; o <<= 1) {
        int x = (t >= o) ? lds[t - o] : 0;
        __syncthreads();
        lds[t] += x;
        __syncthreads();
    }
    if (t < nb) bsum[t] = lds[t] - v;   // exclusive
}

__global__ __launch_bounds__(256) void scan_final_kernel(const int* __restrict__ deg,
    const int* __restrict__ bsum_excl, int* __restrict__ rowptr, int* __restrict__ cursor,
    int Nd, int E)
{
    __shared__ int lds[256];
    int t = threadIdx.x;
    int i = blockIdx.x * 256 + t;
    int v = (i < Nd) ? deg[i] : 0;
    lds[t] = v;
    __syncthreads();
    for (int o = 1; o < 256; o <<= 1) {
        int x = (t >= o) ? lds[t - o] : 0;
        __syncthreads();
        lds[t] += x;
        __syncthreads();
    }
    int excl = lds[t] - v + bsum_excl[blockIdx.x];
    if (i < Nd) {
        rowptr[i] = excl;
        cursor[i] = excl;
        if (i == Nd - 1) rowptr[Nd] = E;
    }
}

__global__ __launch_bounds__(256) void scatter_kernel(const int* __restrict__ src,
    const int* __restrict__ dst, int* __restrict__ cursor, int* __restrict__ csr, int E)
{
    int e = blockIdx.x * 256 + threadIdx.x;
    if (e < E) {
        int p = atomicAdd(&cursor[dst[e]], 1);
        csr[p] = src[e];
    }
}

// ================= conv1 aggregation: one wave per dst node (high occupancy) =================
__device__ __forceinline__ void acc_edge(int s, int lane,
    const float* __restrict__ als, const float* __restrict__ hsrc, const float4& A,
    float& a0, float& a1, float& a2, float& a3,
    float& w0, float& w1, float& w2, float& w3)
{
    float4 v = *(const float4*)(als + (size_t)s * 4);
    float x = hsrc[(size_t)s * 64 + lane];
    float e0 = lrelu_exp(v.x + A.x);
    float e1 = lrelu_exp(v.y + A.y);
    float e2 = lrelu_exp(v.z + A.z);
    float e3 = lrelu_exp(v.w + A.w);
    a0 = fmaf(e0, x, a0); w0 += e0;
    a1 = fmaf(e1, x, a1); w1 += e1;
    a2 = fmaf(e2, x, a2); w2 += e2;
    a3 = fmaf(e3, x, a3); w3 += e3;
}

__global__ __launch_bounds__(256) void agg_conv1_kernel(const int* __restrict__ rowptr,
    const int* __restrict__ csr, const float* __restrict__ hsrc,
    const float* __restrict__ als, const float* __restrict__ ald,
    float* __restrict__ agg, int Nd)
{
    int d = blockIdx.x * 4 + (threadIdx.x >> 6);
    int lane = threadIdx.x & 63;
    if (d >= Nd) return;
    int beg = rowptr[d], end = rowptr[d + 1];
    float4 A = *(const float4*)(ald + (size_t)d * 4);
    float a0 = 0.f, a1 = 0.f, a2 = 0.f, a3 = 0.f;
    float w0 = 0.f, w1 = 0.f, w2 = 0.f, w3 = 0.f;
    int i = beg;
    for (; i + 2 <= end; i += 2) {
        acc_edge(csr[i],     lane, als, hsrc, A, a0, a1, a2, a3, w0, w1, w2, w3);
        acc_edge(csr[i + 1], lane, als, hsrc, A, a0, a1, a2, a3, w0, w1, w2, w3);
    }
    if (i < end)
        acc_edge(csr[i], lane, als, hsrc, A, a0, a1, a2, a3, w0, w1, w2, w3);
    float* o = agg + (size_t)d * 256;
    o[lane]       = a0 / (w0 + 1e-16f);
    o[64 + lane]  = a1 / (w1 + 1e-16f);
    o[128 + lane] = a2 / (w2 + 1e-16f);
    o[192 + lane] = a3 / (w3 + 1e-16f);
}

// ---------- stage A: coalesced-load 64 agg rows into swizzled LDS tile ----------
__device__ __forceinline__ void stage_tile(const float* __restrict__ agg, float* sT,
                                           int base, int Nd, int w, int lane)
{
    #pragma unroll 4
    for (int it = 0; it < 16; ++it) {
        int rl = w * 16 + it;
        int gr = base + rl;
        const float* arow = agg + (size_t)gr * 256;
        #pragma unroll
        for (int seg = 0; seg < 4; ++seg) {
            int col = seg * 64 + lane;
            sT[sidx(col, rl)] = (gr < Nd) ? arow[col] : 0.f;
        }
    }
}

// ================= conv1 u2t transform: per-head GEMM + elu + dot (t1 never stored) ============
__global__ __launch_bounds__(256, 2) void transform_u2t(
    const float* __restrict__ agg, const float* __restrict__ W1,
    const float* __restrict__ b1, const float* __restrict__ vvec,
    float* __restrict__ dot_out, int Nd)
{
    __shared__ float sT[256 * 64];
    const int tid = threadIdx.x;
    const int lane = tid & 63;
    const int w = tid >> 6;
    const int base = blockIdx.x * 64;

    stage_tile(agg, sT, base, Nd, w, lane);
    __syncthreads();

    const int h = w, nl = lane;       // thread -> (node = lane, head = wave); W rows SGPR-uniform
    float acc[64];
    const float* brow = b1 + h * 64;
    #pragma unroll
    for (int j = 0; j < 64; ++j) acc[j] = brow[j];
    #pragma unroll 1
    for (int c = 0; c < 64; ++c) {
        float xc = sT[sidx(h * 64 + c, nl)];
        const float* wrow = W1 + (size_t)c * 256 + h * 64;
        #pragma unroll
        for (int j = 0; j < 64; ++j) acc[j] = fmaf(xc, wrow[j], acc[j]);
    }
    float dsum = 0.f;
    const float* vrow = vvec + h * 64;
    #pragma unroll
    for (int j = 0; j < 64; ++j) {
        float v = acc[j];
        v = v > 0.f ? v : (expf(v) - 1.f);
        dsum += v * vrow[j];
    }
    __syncthreads();
    sT[h * 64 + nl] = dsum;
    __syncthreads();
    if (tid < 64 && base + tid < Nd)
        dot_out[base + tid] = sT[tid] + sT[64 + tid] + sT[128 + tid] + sT[192 + tid];
}

// ================= conv1 t2u transform + conv2 projection (u1 never stored) ====================
__global__ __launch_bounds__(256, 2) void transform_t2u(
    const float* __restrict__ agg, const float* __restrict__ W1,
    const float* __restrict__ b1, const float* __restrict__ W2,
    const float* __restrict__ as2,
    float* __restrict__ hs2, float* __restrict__ als2, int Nd)
{
    __shared__ float sT[256 * 64];
    const int tid = threadIdx.x;
    const int lane = tid & 63;
    const int w = tid >> 6;
    const int base = blockIdx.x * 64;

    stage_tile(agg, sT, base, Nd, w, lane);
    __syncthreads();

    const int h = w, nl = lane;
    {
        float acc[64];
        const float* brow = b1 + h * 64;
        #pragma unroll
        for (int j = 0; j < 64; ++j) acc[j] = brow[j];
        #pragma unroll 1
        for (int c = 0; c < 64; ++c) {
            float xc = sT[sidx(h * 64 + c, nl)];
            const float* wrow = W1 + (size_t)c * 256 + h * 64;
            #pragma unroll
            for (int j = 0; j < 64; ++j) acc[j] = fmaf(xc, wrow[j], acc[j]);
        }
        // own cells only -> no barrier needed before writes
        #pragma unroll
        for (int j = 0; j < 64; ++j) {
            float v = acc[j];
            sT[sidx(h * 64 + j, nl)] = v > 0.f ? v : (expf(v) - 1.f);
        }
    }
    __syncthreads();

    // stage 3: hs2 = u1 @ W2 (node = lane, col-group = w), als2 = hs2 . as2
    float o8[8] = {0.f, 0.f, 0.f, 0.f, 0.f, 0.f, 0.f, 0.f};
    #pragma unroll 1
    for (int k = 0; k < 256; ++k) {
        float x = sT[sidx(k, nl)];
        const float* w2r = W2 + (size_t)k * 32 + w * 8;   // wave-uniform
        #pragma unroll
        for (int m = 0; m < 8; ++m) o8[m] = fmaf(x, w2r[m], o8[m]);
    }
    const int d = base + nl;
    float p = 0.f;
    #pragma unroll
    for (int m = 0; m < 8; ++m) p += o8[m] * as2[w * 8 + m];
    if (d < Nd) {
        float4 oa = make_float4(o8[0], o8[1], o8[2], o8[3]);
        float4 ob = make_float4(o8[4], o8[5], o8[6], o8[7]);
        *(float4*)(hs2 + (size_t)d * 32 + w * 8)     = oa;
        *(float4*)(hs2 + (size_t)d * 32 + w * 8 + 4) = ob;
    }
    __syncthreads();
    sT[w * 64 + nl] = p;
    __syncthreads();
    if (tid < 64 && base + tid < Nd)
        als2[base + tid] = sT[tid] + sT[64 + tid] + sT[128 + tid] + sT[192 + tid];
}

// ================= conv2: fused edge-softmax + aggregation + bias/ELU + classifier ==========
__global__ __launch_bounds__(256) void conv2_fused_kernel(const int* __restrict__ rowptr,
    const int* __restrict__ csr, const float* __restrict__ hs2,
    const float* __restrict__ als2, const float* __restrict__ ald2,
    const float* __restrict__ b2, const float* __restrict__ Wc, const float* __restrict__ bc,
    float* __restrict__ out, int Nd)
{
    int d = blockIdx.x * 4 + (threadIdx.x >> 6);
    int lane = threadIdx.x & 63;
    if (d >= Nd) return;
    int beg = rowptr[d], end = rowptr[d + 1];
    float aldd = ald2[d];
    int half = lane >> 5, c = lane & 31;
    float acc = 0.f, wsum = 0.f;
    for (int i = beg + half; i < end; i += 2) {
        int s = csr[i];
        float w = lrelu_exp(als2[s] + aldd);
        acc = fmaf(w, hs2[(size_t)s * 32 + c], acc);
        wsum += w;
    }
    acc  += __shfl_down(acc, 32);
    wsum += __shfl_down(wsum, 32);
    float val = 0.f;
    if (lane < 32) {
        float t2 = acc / (wsum + 1e-16f) + b2[c];
        t2 = t2 > 0.f ? t2 : (expf(t2) - 1.f);
        val = t2 * Wc[c];
    }
    #pragma unroll
    for (int o = 16; o > 0; o >>= 1) val += __shfl_down(val, o);
    if (lane == 0) out[d] = val + bc[0];
}

extern "C" void kernel_launch(void* const* d_in, const int* in_sizes, int n_in,
                              void* d_out, int out_size, void* d_ws, size_t ws_size,
                              hipStream_t stream)
{
    const float* x_tx    = (const float*)d_in[0];
    const float* x_user  = (const float*)d_in[1];
    const int*   ei_u2t  = (const int*)d_in[2];
    const int*   ei_t2u  = (const int*)d_in[3];
    const float* Wp_tx   = (const float*)d_in[4];
    const float* bp_tx   = (const float*)d_in[5];
    const float* Wp_user = (const float*)d_in[6];
    const float* bp_user = (const float*)d_in[7];
    const float* W1_u2t  = (const float*)d_in[8];
    const float* as1_u2t = (const float*)d_in[9];
    const float* ad1_u2t = (const float*)d_in[10];
    const float* b1_u2t  = (const float*)d_in[11];
    const float* W2_u2t  = (const float*)d_in[12];
    const float* as2_u2t = (const float*)d_in[13];
    const float* ad2_u2t = (const float*)d_in[14];
    const float* b2_u2t  = (const float*)d_in[15];
    const float* W1_t2u  = (const float*)d_in[16];
    const float* as1_t2u = (const float*)d_in[17];
    const float* ad1_t2u = (const float*)d_in[18];
    const float* b1_t2u  = (const float*)d_in[19];
    const float* Wc      = (const float*)d_in[24];
    const float* bc      = (const float*)d_in[25];
    float* out = (float*)d_out;
    float* ws  = (float*)d_ws;

    const int* src_u2t = ei_u2t;            // user ids
    const int* dst_u2t = ei_u2t + NE;       // tx ids
    const int* src_t2u = ei_t2u;            // tx ids
    const int* dst_u   = ei_t2u + NE;       // user ids

    // ---- workspace layout (floats); total ~39.7M floats = 158.8 MB ----
    float* h_tx   = ws;                     //  6,400,000
    float* h_us   = ws + 6400000;           //  3,200,000
    float* hs2    = ws + 9600000;           //  1,600,000
    float* als2   = ws + 11200000;          //     50,000
    float* ald2   = ws + 11250000;          //    100,000
    float* als_us = ws + 11350000;          //    200,000  (user src-attn for u2t)
    float* ald_us = ws + 11550000;          //    200,000  (user dst-attn for t2u)
    float* als_tx = ws + 11750000;          //    400,000  (tx src-attn for t2u)
    float* ald_tx = ws + 12150000;          //    400,000  (tx dst-attn for u2t)
    float* agg    = ws + 12550000;          // 25,600,000  (u2t then t2u, sequential)
    float* avec   = ws + 38150000;          //      1,536
    // ---- int region ----
    int* ibase    = (int*)(ws + 38152000);
    int* deg_t    = ibase;                  //   100,000
    int* deg_u    = ibase + 100000;         //    50,000
    int* rowptr_t = ibase + 150000;         //   100,001
    int* cur_t    = ibase + 250001;         //   100,000
    int* csr_t    = ibase + 350001;         //   500,000
    int* rowptr_u = ibase + 850001;         //    50,001
    int* cur_u    = ibase + 900002;         //    50,000
    int* csr_u    = ibase + 950002;         //   500,000
    int* bsum_t   = ibase + 1450002;        //       512
    int* bsum_u   = ibase + 1450514;        //       512

    float* Msrc_u2t = avec + 0;
    float* Mdst_u2t = avec + 256;
    float* Msrc_t2u = avec + 512;
    float* Mdst_t2u = avec + 768;
    float* vdst2    = avec + 1280;

    const int NB_T = (N_TX + 255) / 256;    // 391
    const int NB_U = (N_USER + 255) / 256;  // 196

    // ---- fold attention vectors into weights ----
    AVArgs6 av;
    av.t[0] = { W1_u2t, as1_u2t, Msrc_u2t, HID, NH, HID };
    av.t[1] = { W1_u2t, ad1_u2t, Mdst_u2t, HID, NH, HID };
    av.t[2] = { W1_t2u, as1_t2u, Msrc_t2u, HID, NH, HID };
    av.t[3] = { W1_t2u, ad1_t2u, Mdst_t2u, HID, NH, HID };
    av.t[4] = { W2_u2t, as2_u2t, avec + 1024, HC1, 1, OUTC };
    av.t[5] = { W2_u2t, ad2_u2t, vdst2, HC1, 1, OUTC };
    attn_vecs_kernel<<<6, 256, 0, stream>>>(av);

    // ---- zero degree histograms ----
    hipMemsetAsync(deg_t, 0, 150000 * sizeof(int), stream);

    // ---- CSR build for u2t (dst = tx) ----
    hist_kernel<<<(NE + 255) / 256, 256, 0, stream>>>(dst_u2t, deg_t, NE);
    block_sum_kernel<<<NB_T, 256, 0, stream>>>(deg_t, bsum_t, N_TX);
    scan_bsum_kernel<<<1, 512, 0, stream>>>(bsum_t, NB_T);
    scan_final_kernel<<<NB_T, 256, 0, stream>>>(deg_t, bsum_t, rowptr_t, cur_t, N_TX, NE);
    scatter_kernel<<<(NE + 255) / 256, 256, 0, stream>>>(src_u2t, dst_u2t, cur_t, csr_t, NE);

    // ---- CSR build for t2u (dst = user) ----
    hist_kernel<<<(NE + 255) / 256, 256, 0, stream>>>(dst_u, deg_u, NE);
    block_sum_kernel<<<NB_U, 256, 0, stream>>>(deg_u, bsum_u, N_USER);
    scan_bsum_kernel<<<1, 512, 0, stream>>>(bsum_u, NB_U);
    scan_final_kernel<<<NB_U, 256, 0, stream>>>(deg_u, bsum_u, rowptr_u, cur_u, N_USER, NE);
    scatter_kernel<<<(NE + 255) / 256, 256, 0, stream>>>(src_t2u, dst_u, cur_u, csr_u, NE);

    // ---- input projections ----
    gemm_kernel<<<dim3(1, (N_TX + 63) / 64), 256, 0, stream>>>(
        x_tx, Wp_tx, bp_tx, h_tx, N_TX, F_TX, HID, 1);
    gemm_kernel<<<dim3(1, (N_USER + 63) / 64), 256, 0, stream>>>(
        x_user, Wp_user, bp_user, h_us, N_USER, F_USER, HID, 1);

    // ---- node attention scalars (both edge types per node type, one pass) ----
    node_attn8<<<(N_USER + 3) / 4, 256, 0, stream>>>(
        h_us, Msrc_u2t, Mdst_t2u, als_us, ald_us, N_USER);
    node_attn8<<<(N_TX + 3) / 4, 256, 0, stream>>>(
        h_tx, Mdst_u2t, Msrc_t2u, ald_tx, als_tx, N_TX);

    // ================= conv1, u2t (dst = tx): agg then transform -> ald2 ==========
    agg_conv1_kernel<<<(N_TX + 3) / 4, 256, 0, stream>>>(
        rowptr_t, csr_t, h_us, als_us, ald_tx, agg, N_TX);
    transform_u2t<<<(N_TX + 63) / 64, 256, 0, stream>>>(
        agg, W1_u2t, b1_u2t, vdst2, ald2, N_TX);

    // ================= conv1, t2u (dst = user): agg then transform -> hs2, als2 ==========
    agg_conv1_kernel<<<(N_USER + 3) / 4, 256, 0, stream>>>(
        rowptr_u, csr_u, h_tx, als_tx, ald_us, agg, N_USER);
    transform_t2u<<<(N_USER + 63) / 64, 256, 0, stream>>>(
        agg, W1_t2u, b1_t2u, W2_u2t, as2_u2t, hs2, als2, N_USER);

    // ================= conv2 + classifier =================
    conv2_fused_kernel<<<(N_TX + 3) / 4, 256, 0, stream>>>(
        rowptr_t, csr_t, hs2, als2, ald2, b2_u2t, Wc, bc, out, N_TX);
}

// Round 6
// 861.115 us; speedup vs baseline: 1.3613x; 1.2388x over previous
//
#include <hip/hip_runtime.h>
#include <hip/hip_bf16.h>
#include <math.h>

#define N_TX   100000
#define N_USER 50000
#define F_TX   128
#define F_USER 64
#define HID    64
#define NH     4
#define OUTC   32
#define NE     500000
#define HC1    256          // NH*HID
#define SLOPE  0.2f

__device__ __forceinline__ float elu_f(float x) { return x > 0.f ? x : (expf(x) - 1.f); }
__device__ __forceinline__ float lrelu_exp(float x) { x = x > 0.f ? x : SLOPE * x; return expf(x); }

// ---------------- tiled fp32 GEMM: C = act(A[N,K] @ B[K,M] + bias) ----------------
__global__ __launch_bounds__(256) void gemm_kernel(const float* __restrict__ A,
    const float* __restrict__ B, const float* __restrict__ bias,
    float* __restrict__ C, int N, int K, int M, int act)
{
    __shared__ float As[16][65];
    __shared__ float Bs[16][65];
    const int tid = threadIdx.x;
    const int tx = tid % 16, ty = tid / 16;
    const int row0 = blockIdx.y * 64, col0 = blockIdx.x * 64;
    float acc[4][4] = {};
    for (int k0 = 0; k0 < K; k0 += 16) {
        #pragma unroll
        for (int i = 0; i < 4; ++i) {
            int idx = tid * 4 + i;           // 64x16 A tile
            int r = idx >> 4, kk = idx & 15;
            int gr = row0 + r;
            As[kk][r] = (gr < N) ? A[(size_t)gr * K + (k0 + kk)] : 0.f;
        }
        #pragma unroll
        for (int i = 0; i < 4; ++i) {
            int idx = tid * 4 + i;           // 16x64 B tile
            int kk = idx >> 6, c = idx & 63;
            int gc = col0 + c;
            Bs[kk][c] = (gc < M) ? B[(size_t)(k0 + kk) * M + gc] : 0.f;
        }
        __syncthreads();
        #pragma unroll
        for (int kk = 0; kk < 16; ++kk) {
            float a4[4], b4[4];
            #pragma unroll
            for (int i = 0; i < 4; ++i) a4[i] = As[kk][ty * 4 + i];
            #pragma unroll
            for (int j = 0; j < 4; ++j) b4[j] = Bs[kk][tx * 4 + j];
            #pragma unroll
            for (int i = 0; i < 4; ++i)
                #pragma unroll
                for (int j = 0; j < 4; ++j) acc[i][j] += a4[i] * b4[j];
        }
        __syncthreads();
    }
    #pragma unroll
    for (int i = 0; i < 4; ++i) {
        int r = row0 + ty * 4 + i;
        if (r >= N) continue;
        #pragma unroll
        for (int j = 0; j < 4; ++j) {
            int c = col0 + tx * 4 + j;
            if (c >= M) continue;
            float v = acc[i][j] + (bias ? bias[c] : 0.f);
            if (act == 1) v = elu_f(v);
            C[(size_t)r * M + c] = v;
        }
    }
}

// ------------- fold attention vectors into weights: Mv[k,h] = sum_c W[k,h*C+c]*a[h,c] -------------
struct AVArgs  { const float* W; const float* a; float* out; int K; int H; int C; };
struct AVArgs6 { AVArgs t[6]; };

__global__ void attn_vecs_kernel(AVArgs6 args)
{
    AVArgs A = args.t[blockIdx.x];
    int tid = threadIdx.x;
    if (tid < A.K * A.H) {
        int k = tid % A.K, h = tid / A.K;
        float s = 0.f;
        const float* wrow = A.W + (size_t)k * (A.H * A.C) + h * A.C;
        const float* arow = A.a + h * A.C;
        for (int c = 0; c < A.C; ++c) s += wrow[c] * arow[c];
        A.out[k * A.H + h] = s;
    }
}

// ------------- per-node attention scalars, K=64, two head-quads in one pass -------------
__global__ void node_attn8(const float* __restrict__ X, const float* __restrict__ Mva,
    const float* __restrict__ Mvb, float* __restrict__ outa, float* __restrict__ outb, int N)
{
    int wave = blockIdx.x * (blockDim.x >> 6) + (threadIdx.x >> 6);
    int lane = threadIdx.x & 63;
    if (wave >= N) return;
    float x = X[(size_t)wave * 64 + lane];
    float a0 = x * Mva[lane * 4 + 0];
    float a1 = x * Mva[lane * 4 + 1];
    float a2 = x * Mva[lane * 4 + 2];
    float a3 = x * Mva[lane * 4 + 3];
    float b0 = x * Mvb[lane * 4 + 0];
    float b1 = x * Mvb[lane * 4 + 1];
    float b2 = x * Mvb[lane * 4 + 2];
    float b3 = x * Mvb[lane * 4 + 3];
    for (int off = 32; off > 0; off >>= 1) {
        a0 += __shfl_down(a0, off); a1 += __shfl_down(a1, off);
        a2 += __shfl_down(a2, off); a3 += __shfl_down(a3, off);
        b0 += __shfl_down(b0, off); b1 += __shfl_down(b1, off);
        b2 += __shfl_down(b2, off); b3 += __shfl_down(b3, off);
    }
    if (lane == 0) {
        float* oa = outa + (size_t)wave * 4;
        oa[0] = a0; oa[1] = a1; oa[2] = a2; oa[3] = a3;
        float* ob = outb + (size_t)wave * 4;
        ob[0] = b0; ob[1] = b1; ob[2] = b2; ob[3] = b3;
    }
}

// ================= CSR build =================
__global__ __launch_bounds__(256) void hist_kernel(const int* __restrict__ dst,
    int* __restrict__ deg, int E)
{
    int e = blockIdx.x * 256 + threadIdx.x;
    if (e < E) atomicAdd(&deg[dst[e]], 1);
}

__global__ __launch_bounds__(256) void block_sum_kernel(const int* __restrict__ deg,
    int* __restrict__ bsum, int Nd)
{
    __shared__ int lds[256];
    int t = threadIdx.x;
    int i = blockIdx.x * 256 + t;
    lds[t] = (i < Nd) ? deg[i] : 0;
    __syncthreads();
    for (int o = 128; o > 0; o >>= 1) {
        if (t < o) lds[t] += lds[t + o];
        __syncthreads();
    }
    if (t == 0) bsum[blockIdx.x] = lds[0];
}

__global__ __launch_bounds__(512) void scan_bsum_kernel(int* __restrict__ bsum, int nb)
{
    __shared__ int lds[512];
    int t = threadIdx.x;
    int v = (t < nb) ? bsum[t] : 0;
    lds[t] = v;
    __syncthreads();
    for (int o = 1; o < 512; o <<= 1) {
        int x = (t >= o) ? lds[t - o] : 0;
        __syncthreads();
        lds[t] += x;
        __syncthreads();
    }
    if (t < nb) bsum[t] = lds[t] - v;   // exclusive
}

__global__ __launch_bounds__(256) void scan_final_kernel(const int* __restrict__ deg,
    const int* __restrict__ bsum_excl, int* __restrict__ rowptr, int* __restrict__ cursor,
    int Nd, int E)
{
    __shared__ int lds[256];
    int t = threadIdx.x;
    int i = blockIdx.x * 256 + t;
    int v = (i < Nd) ? deg[i] : 0;
    lds[t] = v;
    __syncthreads();
    for (int o = 1; o < 256; o <<= 1) {
        int x = (t >= o) ? lds[t - o] : 0;
        __syncthreads();
        lds[t] += x;
        __syncthreads();
    }
    int excl = lds[t] - v + bsum_excl[blockIdx.x];
    if (i < Nd) {
        rowptr[i] = excl;
        cursor[i] = excl;
        if (i == Nd - 1) rowptr[Nd] = E;
    }
}

__global__ __launch_bounds__(256) void scatter_kernel(const int* __restrict__ src,
    const int* __restrict__ dst, int* __restrict__ cursor, int* __restrict__ csr, int E)
{
    int e = blockIdx.x * 256 + threadIdx.x;
    if (e < E) {
        int p = atomicAdd(&cursor[dst[e]], 1);
        csr[p] = src[e];
    }
}

// ================= conv1 aggregation: one wave per dst node (high occupancy) =================
__device__ __forceinline__ void acc_edge(int s, int lane,
    const float* __restrict__ als, const float* __restrict__ hsrc, const float4& A,
    float& a0, float& a1, float& a2, float& a3,
    float& w0, float& w1, float& w2, float& w3)
{
    float4 v = *(const float4*)(als + (size_t)s * 4);
    float x = hsrc[(size_t)s * 64 + lane];
    float e0 = lrelu_exp(v.x + A.x);
    float e1 = lrelu_exp(v.y + A.y);
    float e2 = lrelu_exp(v.z + A.z);
    float e3 = lrelu_exp(v.w + A.w);
    a0 = fmaf(e0, x, a0); w0 += e0;
    a1 = fmaf(e1, x, a1); w1 += e1;
    a2 = fmaf(e2, x, a2); w2 += e2;
    a3 = fmaf(e3, x, a3); w3 += e3;
}

__global__ __launch_bounds__(256) void agg_conv1_kernel(const int* __restrict__ rowptr,
    const int* __restrict__ csr, const float* __restrict__ hsrc,
    const float* __restrict__ als, const float* __restrict__ ald,
    float* __restrict__ agg, int Nd)
{
    int d = blockIdx.x * 4 + (threadIdx.x >> 6);
    int lane = threadIdx.x & 63;
    if (d >= Nd) return;
    int beg = rowptr[d], end = rowptr[d + 1];
    float4 A = *(const float4*)(ald + (size_t)d * 4);
    float a0 = 0.f, a1 = 0.f, a2 = 0.f, a3 = 0.f;
    float w0 = 0.f, w1 = 0.f, w2 = 0.f, w3 = 0.f;
    int i = beg;
    for (; i + 2 <= end; i += 2) {
        acc_edge(csr[i],     lane, als, hsrc, A, a0, a1, a2, a3, w0, w1, w2, w3);
        acc_edge(csr[i + 1], lane, als, hsrc, A, a0, a1, a2, a3, w0, w1, w2, w3);
    }
    if (i < end)
        acc_edge(csr[i], lane, als, hsrc, A, a0, a1, a2, a3, w0, w1, w2, w3);
    float* o = agg + (size_t)d * 256;
    o[lane]       = a0 / (w0 + 1e-16f);
    o[64 + lane]  = a1 / (w1 + 1e-16f);
    o[128 + lane] = a2 / (w2 + 1e-16f);
    o[192 + lane] = a3 / (w3 + 1e-16f);
}

// ================= conv1 dst-side transform, v2: W in VGPRs, x via LDS broadcast ============
// Block = 64 nodes; wave w = head h. Lane j holds W1[:, h*64+j] in 64 VGPRs.
// Per node: t_hj = elu(sum_c x[h*64+c]*W1[c][h*64+j] + b1[h*64+j]);
//   dot_part[h*Nd + n] = sum_j t_hj * vvec[h*64+j]
//   if writeRows: rows_out[n*256 + h*64 + j] = t_hj   (u1; rows_out may alias agg)
__global__ __launch_bounds__(256, 2) void transform_v2(
    const float* __restrict__ agg, const float* __restrict__ W1,
    const float* __restrict__ b1, const float* __restrict__ vvec,
    float* __restrict__ dot_part, float* __restrict__ rows_out,
    int Nd, int writeRows)
{
    __shared__ float sX[64 * 256];      // node-major, 64 KiB
    const int tid = threadIdx.x;
    const int lane = tid & 63;
    const int w = tid >> 6;
    const int base = blockIdx.x * 64;

    // stage: one float4 per thread per row-slice; coalesced 1 KB per wave per row
    #pragma unroll 4
    for (int it = 0; it < 16; ++it) {
        int rl = w * 16 + it, gr = base + rl;
        float4 v = make_float4(0.f, 0.f, 0.f, 0.f);
        if (gr < Nd) v = *(const float4*)(agg + (size_t)gr * 256 + lane * 4);
        *(float4*)(sX + rl * 256 + lane * 4) = v;
    }

    // W column into registers (once per block, coalesced)
    float Wreg[64];
    #pragma unroll
    for (int c = 0; c < 64; ++c)
        Wreg[c] = W1[(size_t)c * 256 + w * 64 + lane];
    const float breg = b1[w * 64 + lane];
    const float vreg = vvec[w * 64 + lane];
    __syncthreads();

    float* dp = dot_part + (size_t)w * Nd;

    for (int nn = 0; nn < 64; nn += 2) {
        const float* x0 = sX + nn * 256 + w * 64;
        const float* x1 = x0 + 256;
        float a0 = breg, c0 = 0.f, a1 = breg, c1 = 0.f;   // 4 independent chains
        #pragma unroll
        for (int c = 0; c < 64; c += 8) {
            float4 p0 = *(const float4*)(x0 + c);
            float4 q0 = *(const float4*)(x0 + c + 4);
            float4 p1 = *(const float4*)(x1 + c);
            float4 q1 = *(const float4*)(x1 + c + 4);
            a0 = fmaf(p0.x, Wreg[c],     a0); c0 = fmaf(p0.y, Wreg[c + 1], c0);
            a0 = fmaf(p0.z, Wreg[c + 2], a0); c0 = fmaf(p0.w, Wreg[c + 3], c0);
            a0 = fmaf(q0.x, Wreg[c + 4], a0); c0 = fmaf(q0.y, Wreg[c + 5], c0);
            a0 = fmaf(q0.z, Wreg[c + 6], a0); c0 = fmaf(q0.w, Wreg[c + 7], c0);
            a1 = fmaf(p1.x, Wreg[c],     a1); c1 = fmaf(p1.y, Wreg[c + 1], c1);
            a1 = fmaf(p1.z, Wreg[c + 2], a1); c1 = fmaf(p1.w, Wreg[c + 3], c1);
            a1 = fmaf(q1.x, Wreg[c + 4], a1); c1 = fmaf(q1.y, Wreg[c + 5], c1);
            a1 = fmaf(q1.z, Wreg[c + 6], a1); c1 = fmaf(q1.w, Wreg[c + 7], c1);
        }
        float v0 = a0 + c0; v0 = v0 > 0.f ? v0 : (expf(v0) - 1.f);
        float v1 = a1 + c1; v1 = v1 > 0.f ? v1 : (expf(v1) - 1.f);
        int g0 = base + nn, g1 = g0 + 1;
        if (writeRows) {
            if (g0 < Nd) rows_out[(size_t)g0 * 256 + w * 64 + lane] = v0;
            if (g1 < Nd) rows_out[(size_t)g1 * 256 + w * 64 + lane] = v1;
        }
        float s0 = v0 * vreg, s1 = v1 * vreg;
        #pragma unroll
        for (int off = 32; off > 0; off >>= 1) {
            s0 += __shfl_down(s0, off);
            s1 += __shfl_down(s1, off);
        }
        if (lane == 0) {
            if (g0 < Nd) dp[g0] = s0;
            if (g1 < Nd) dp[g1] = s1;
        }
    }
}

// ------------- sum 4 head partials: o1[i] = sum_h ap[h*N1+i]; o2 likewise -------------
__global__ __launch_bounds__(256) void combine_parts(
    const float* __restrict__ ap, float* __restrict__ o1, int N1,
    const float* __restrict__ bp, float* __restrict__ o2, int N2)
{
    int i = blockIdx.x * 256 + threadIdx.x;
    if (i < N1) {
        o1[i] = ap[i] + ap[N1 + i] + ap[2 * N1 + i] + ap[3 * N1 + i];
    } else {
        int j = i - N1;
        if (j < N2)
            o2[j] = bp[j] + bp[N2 + j] + bp[2 * N2 + j] + bp[3 * N2 + j];
    }
}

// ================= conv2: fused edge-softmax + aggregation + bias/ELU + classifier ==========
__global__ __launch_bounds__(256) void conv2_fused_kernel(const int* __restrict__ rowptr,
    const int* __restrict__ csr, const float* __restrict__ hs2,
    const float* __restrict__ als2, const float* __restrict__ ald2,
    const float* __restrict__ b2, const float* __restrict__ Wc, const float* __restrict__ bc,
    float* __restrict__ out, int Nd)
{
    int d = blockIdx.x * 4 + (threadIdx.x >> 6);
    int lane = threadIdx.x & 63;
    if (d >= Nd) return;
    int beg = rowptr[d], end = rowptr[d + 1];
    float aldd = ald2[d];
    int half = lane >> 5, c = lane & 31;
    float acc = 0.f, wsum = 0.f;
    for (int i = beg + half; i < end; i += 2) {
        int s = csr[i];
        float w = lrelu_exp(als2[s] + aldd);
        acc = fmaf(w, hs2[(size_t)s * 32 + c], acc);
        wsum += w;
    }
    acc  += __shfl_down(acc, 32);
    wsum += __shfl_down(wsum, 32);
    float val = 0.f;
    if (lane < 32) {
        float t2 = acc / (wsum + 1e-16f) + b2[c];
        t2 = t2 > 0.f ? t2 : (expf(t2) - 1.f);
        val = t2 * Wc[c];
    }
    #pragma unroll
    for (int o = 16; o > 0; o >>= 1) val += __shfl_down(val, o);
    if (lane == 0) out[d] = val + bc[0];
}

extern "C" void kernel_launch(void* const* d_in, const int* in_sizes, int n_in,
                              void* d_out, int out_size, void* d_ws, size_t ws_size,
                              hipStream_t stream)
{
    const float* x_tx    = (const float*)d_in[0];
    const float* x_user  = (const float*)d_in[1];
    const int*   ei_u2t  = (const int*)d_in[2];
    const int*   ei_t2u  = (const int*)d_in[3];
    const float* Wp_tx   = (const float*)d_in[4];
    const float* bp_tx   = (const float*)d_in[5];
    const float* Wp_user = (const float*)d_in[6];
    const float* bp_user = (const float*)d_in[7];
    const float* W1_u2t  = (const float*)d_in[8];
    const float* as1_u2t = (const float*)d_in[9];
    const float* ad1_u2t = (const float*)d_in[10];
    const float* b1_u2t  = (const float*)d_in[11];
    const float* W2_u2t  = (const float*)d_in[12];
    const float* as2_u2t = (const float*)d_in[13];
    const float* ad2_u2t = (const float*)d_in[14];
    const float* b2_u2t  = (const float*)d_in[15];
    const float* W1_t2u  = (const float*)d_in[16];
    const float* as1_t2u = (const float*)d_in[17];
    const float* ad1_t2u = (const float*)d_in[18];
    const float* b1_t2u  = (const float*)d_in[19];
    const float* Wc      = (const float*)d_in[24];
    const float* bc      = (const float*)d_in[25];
    float* out = (float*)d_out;
    float* ws  = (float*)d_ws;

    const int* src_u2t = ei_u2t;            // user ids
    const int* dst_u2t = ei_u2t + NE;       // tx ids
    const int* src_t2u = ei_t2u;            // tx ids
    const int* dst_u   = ei_t2u + NE;       // user ids

    // ---- workspace layout (floats); total ~39.7M floats = 158.8 MB ----
    float* h_tx   = ws;                     //  6,400,000
    float* h_us   = ws + 6400000;           //  3,200,000
    float* hs2    = ws + 9600000;           //  1,600,000  (ald2p/als2p alias here pre-gemm)
    float* als2   = ws + 11200000;          //     50,000
    float* ald2   = ws + 11250000;          //    100,000
    float* als_us = ws + 11350000;          //    200,000  (user src-attn for u2t)
    float* ald_us = ws + 11550000;          //    200,000  (user dst-attn for t2u)
    float* als_tx = ws + 11750000;          //    400,000  (tx src-attn for t2u)
    float* ald_tx = ws + 12150000;          //    400,000  (tx dst-attn for u2t)
    float* agg    = ws + 12550000;          // 25,600,000  (u2t then t2u; u1 in place)
    float* avec   = ws + 38150000;          //      1,536
    // partials alias the not-yet-live hs2 region (600k <= 1.6M)
    float* ald2p = hs2;                     //    400,000  (4 x N_TX)
    float* als2p = hs2 + 400000;            //    200,000  (4 x N_USER)
    // ---- int region ----
    int* ibase    = (int*)(ws + 38152000);
    int* deg_t    = ibase;                  //   100,000
    int* deg_u    = ibase + 100000;         //    50,000
    int* rowptr_t = ibase + 150000;         //   100,001
    int* cur_t    = ibase + 250001;         //   100,000
    int* csr_t    = ibase + 350001;         //   500,000
    int* rowptr_u = ibase + 850001;         //    50,001
    int* cur_u    = ibase + 900002;         //    50,000
    int* csr_u    = ibase + 950002;         //   500,000
    int* bsum_t   = ibase + 1450002;        //       512
    int* bsum_u   = ibase + 1450514;        //       512

    float* Msrc_u2t = avec + 0;
    float* Mdst_u2t = avec + 256;
    float* Msrc_t2u = avec + 512;
    float* Mdst_t2u = avec + 768;
    float* vsrc2    = avec + 1024;          // fold(W2, as2): als2 = u1 . vsrc2
    float* vdst2    = avec + 1280;          // fold(W2, ad2): ald2 = t1 . vdst2

    const int NB_T = (N_TX + 255) / 256;    // 391
    const int NB_U = (N_USER + 255) / 256;  // 196

    // ---- fold attention vectors into weights ----
    AVArgs6 av;
    av.t[0] = { W1_u2t, as1_u2t, Msrc_u2t, HID, NH, HID };
    av.t[1] = { W1_u2t, ad1_u2t, Mdst_u2t, HID, NH, HID };
    av.t[2] = { W1_t2u, as1_t2u, Msrc_t2u, HID, NH, HID };
    av.t[3] = { W1_t2u, ad1_t2u, Mdst_t2u, HID, NH, HID };
    av.t[4] = { W2_u2t, as2_u2t, vsrc2, HC1, 1, OUTC };
    av.t[5] = { W2_u2t, ad2_u2t, vdst2, HC1, 1, OUTC };
    attn_vecs_kernel<<<6, 256, 0, stream>>>(av);

    // ---- zero degree histograms ----
    hipMemsetAsync(deg_t, 0, 150000 * sizeof(int), stream);

    // ---- CSR build for u2t (dst = tx) ----
    hist_kernel<<<(NE + 255) / 256, 256, 0, stream>>>(dst_u2t, deg_t, NE);
    block_sum_kernel<<<NB_T, 256, 0, stream>>>(deg_t, bsum_t, N_TX);
    scan_bsum_kernel<<<1, 512, 0, stream>>>(bsum_t, NB_T);
    scan_final_kernel<<<NB_T, 256, 0, stream>>>(deg_t, bsum_t, rowptr_t, cur_t, N_TX, NE);
    scatter_kernel<<<(NE + 255) / 256, 256, 0, stream>>>(src_u2t, dst_u2t, cur_t, csr_t, NE);

    // ---- CSR build for t2u (dst = user) ----
    hist_kernel<<<(NE + 255) / 256, 256, 0, stream>>>(dst_u, deg_u, NE);
    block_sum_kernel<<<NB_U, 256, 0, stream>>>(deg_u, bsum_u, N_USER);
    scan_bsum_kernel<<<1, 512, 0, stream>>>(bsum_u, NB_U);
    scan_final_kernel<<<NB_U, 256, 0, stream>>>(deg_u, bsum_u, rowptr_u, cur_u, N_USER, NE);
    scatter_kernel<<<(NE + 255) / 256, 256, 0, stream>>>(src_t2u, dst_u, cur_u, csr_u, NE);

    // ---- input projections ----
    gemm_kernel<<<dim3(1, (N_TX + 63) / 64), 256, 0, stream>>>(
        x_tx, Wp_tx, bp_tx, h_tx, N_TX, F_TX, HID, 1);
    gemm_kernel<<<dim3(1, (N_USER + 63) / 64), 256, 0, stream>>>(
        x_user, Wp_user, bp_user, h_us, N_USER, F_USER, HID, 1);

    // ---- node attention scalars (both edge types per node type, one pass) ----
    node_attn8<<<(N_USER + 3) / 4, 256, 0, stream>>>(
        h_us, Msrc_u2t, Mdst_t2u, als_us, ald_us, N_USER);
    node_attn8<<<(N_TX + 3) / 4, 256, 0, stream>>>(
        h_tx, Mdst_u2t, Msrc_t2u, ald_tx, als_tx, N_TX);

    // ================= conv1, u2t (dst = tx): agg -> transform -> ald2 partials ==========
    agg_conv1_kernel<<<(N_TX + 3) / 4, 256, 0, stream>>>(
        rowptr_t, csr_t, h_us, als_us, ald_tx, agg, N_TX);
    transform_v2<<<(N_TX + 63) / 64, 256, 0, stream>>>(
        agg, W1_u2t, b1_u2t, vdst2, ald2p, nullptr, N_TX, 0);

    // ================= conv1, t2u (dst = user): agg -> transform (u1 in place) ==========
    agg_conv1_kernel<<<(N_USER + 3) / 4, 256, 0, stream>>>(
        rowptr_u, csr_u, h_tx, als_tx, ald_us, agg, N_USER);
    transform_v2<<<(N_USER + 63) / 64, 256, 0, stream>>>(
        agg, W1_t2u, b1_t2u, vsrc2, als2p, agg, N_USER, 1);
    float* u1 = agg;

    // ---- combine head partials ----
    combine_parts<<<(N_TX + N_USER + 255) / 256, 256, 0, stream>>>(
        ald2p, ald2, N_TX, als2p, als2, N_USER);

    // ================= conv2 projection + fused conv2/classifier =================
    gemm_kernel<<<dim3(1, (N_USER + 63) / 64), 256, 0, stream>>>(
        u1, W2_u2t, nullptr, hs2, N_USER, HC1, OUTC, 0);
    conv2_fused_kernel<<<(N_TX + 3) / 4, 256, 0, stream>>>(
        rowptr_t, csr_t, hs2, als2, ald2, b2_u2t, Wc, bc, out, N_TX);
}

// Round 7
// 808.509 us; speedup vs baseline: 1.4498x; 1.0651x over previous
//
#include <hip/hip_runtime.h>
#include <hip/hip_bf16.h>
#include <math.h>

#define N_TX   100000
#define N_USER 50000
#define F_TX   128
#define F_USER 64
#define HID    64
#define NH     4
#define OUTC   32
#define NE     500000
#define HC1    256          // NH*HID
#define SLOPE  0.2f
#define NB_T   391          // (N_TX+255)/256
#define NB_U   196          // (N_USER+255)/256

__device__ __forceinline__ float elu_f(float x) { return x > 0.f ? x : (expf(x) - 1.f); }
__device__ __forceinline__ float lrelu_exp(float x) { x = x > 0.f ? x : SLOPE * x; return expf(x); }

// ---------------- tiled fp32 GEMM: C = act(A[N,K] @ B[K,M] + bias) ----------------
__global__ __launch_bounds__(256) void gemm_kernel(const float* __restrict__ A,
    const float* __restrict__ B, const float* __restrict__ bias,
    float* __restrict__ C, int N, int K, int M, int act)
{
    __shared__ float As[16][65];
    __shared__ float Bs[16][65];
    const int tid = threadIdx.x;
    const int tx = tid % 16, ty = tid / 16;
    const int row0 = blockIdx.y * 64, col0 = blockIdx.x * 64;
    float acc[4][4] = {};
    for (int k0 = 0; k0 < K; k0 += 16) {
        #pragma unroll
        for (int i = 0; i < 4; ++i) {
            int idx = tid * 4 + i;           // 64x16 A tile
            int r = idx >> 4, kk = idx & 15;
            int gr = row0 + r;
            As[kk][r] = (gr < N) ? A[(size_t)gr * K + (k0 + kk)] : 0.f;
        }
        #pragma unroll
        for (int i = 0; i < 4; ++i) {
            int idx = tid * 4 + i;           // 16x64 B tile
            int kk = idx >> 6, c = idx & 63;
            int gc = col0 + c;
            Bs[kk][c] = (gc < M) ? B[(size_t)(k0 + kk) * M + gc] : 0.f;
        }
        __syncthreads();
        #pragma unroll
        for (int kk = 0; kk < 16; ++kk) {
            float a4[4], b4[4];
            #pragma unroll
            for (int i = 0; i < 4; ++i) a4[i] = As[kk][ty * 4 + i];
            #pragma unroll
            for (int j = 0; j < 4; ++j) b4[j] = Bs[kk][tx * 4 + j];
            #pragma unroll
            for (int i = 0; i < 4; ++i)
                #pragma unroll
                for (int j = 0; j < 4; ++j) acc[i][j] += a4[i] * b4[j];
        }
        __syncthreads();
    }
    #pragma unroll
    for (int i = 0; i < 4; ++i) {
        int r = row0 + ty * 4 + i;
        if (r >= N) continue;
        #pragma unroll
        for (int j = 0; j < 4; ++j) {
            int c = col0 + tx * 4 + j;
            if (c >= M) continue;
            float v = acc[i][j] + (bias ? bias[c] : 0.f);
            if (act == 1) v = elu_f(v);
            C[(size_t)r * M + c] = v;
        }
    }
}

// ------------- fold attention vectors into weights: Mv[k,h] = sum_c W[k,h*C+c]*a[h,c] -------------
struct AVArgs  { const float* W; const float* a; float* out; int K; int H; int C; };
struct AVArgs6 { AVArgs t[6]; };

__global__ void attn_vecs_kernel(AVArgs6 args)
{
    AVArgs A = args.t[blockIdx.x];
    int tid = threadIdx.x;
    if (tid < A.K * A.H) {
        int k = tid % A.K, h = tid / A.K;
        float s = 0.f;
        const float* wrow = A.W + (size_t)k * (A.H * A.C) + h * A.C;
        const float* arow = A.a + h * A.C;
        for (int c = 0; c < A.C; ++c) s += wrow[c] * arow[c];
        A.out[k * A.H + h] = s;
    }
}

// ------------- per-node attention scalars for BOTH node types in one launch -------------
__global__ __launch_bounds__(256) void node_attn8_dual(
    const float* __restrict__ Xt, const float* __restrict__ Mta, const float* __restrict__ Mtb,
    float* __restrict__ ota, float* __restrict__ otb,
    const float* __restrict__ Xu, const float* __restrict__ Mua, const float* __restrict__ Mub,
    float* __restrict__ oua, float* __restrict__ oub)
{
    int wave = blockIdx.x * 4 + (threadIdx.x >> 6);
    int lane = threadIdx.x & 63;
    const float* X; const float* Ma; const float* Mb; float* oa; float* ob;
    if (wave < N_TX) {              // N_TX % 4 == 0 -> wave-uniform branch per block
        X = Xt + (size_t)wave * 64; Ma = Mta; Mb = Mtb;
        oa = ota + (size_t)wave * 4; ob = otb + (size_t)wave * 4;
    } else {
        int n = wave - N_TX;
        if (n >= N_USER) return;
        X = Xu + (size_t)n * 64; Ma = Mua; Mb = Mub;
        oa = oua + (size_t)n * 4; ob = oub + (size_t)n * 4;
    }
    float x = X[lane];
    float a0 = x * Ma[lane * 4 + 0];
    float a1 = x * Ma[lane * 4 + 1];
    float a2 = x * Ma[lane * 4 + 2];
    float a3 = x * Ma[lane * 4 + 3];
    float b0 = x * Mb[lane * 4 + 0];
    float b1 = x * Mb[lane * 4 + 1];
    float b2 = x * Mb[lane * 4 + 2];
    float b3 = x * Mb[lane * 4 + 3];
    for (int off = 32; off > 0; off >>= 1) {
        a0 += __shfl_down(a0, off); a1 += __shfl_down(a1, off);
        a2 += __shfl_down(a2, off); a3 += __shfl_down(a3, off);
        b0 += __shfl_down(b0, off); b1 += __shfl_down(b1, off);
        b2 += __shfl_down(b2, off); b3 += __shfl_down(b3, off);
    }
    if (lane == 0) {
        oa[0] = a0; oa[1] = a1; oa[2] = a2; oa[3] = a3;
        ob[0] = b0; ob[1] = b1; ob[2] = b2; ob[3] = b3;
    }
}

// ================= merged CSR build (both edge types per launch) =================
__global__ __launch_bounds__(256) void hist2_kernel(const int* __restrict__ dst_t,
    const int* __restrict__ dst_u, int* __restrict__ deg_t, int* __restrict__ deg_u)
{
    int e = blockIdx.x * 256 + threadIdx.x;
    if (e < NE) atomicAdd(&deg_t[dst_t[e]], 1);
    else {
        e -= NE;
        if (e < NE) atomicAdd(&deg_u[dst_u[e]], 1);
    }
}

__global__ __launch_bounds__(256) void block_sum2_kernel(const int* __restrict__ deg_t,
    int* __restrict__ bsum_t, const int* __restrict__ deg_u, int* __restrict__ bsum_u)
{
    __shared__ int lds[256];
    int b = blockIdx.x, t = threadIdx.x;
    const int* deg; int* bsum; int Nd, lb;
    if (b < NB_T) { deg = deg_t; bsum = bsum_t; Nd = N_TX; lb = b; }
    else         { deg = deg_u; bsum = bsum_u; Nd = N_USER; lb = b - NB_T; }
    int i = lb * 256 + t;
    lds[t] = (i < Nd) ? deg[i] : 0;
    __syncthreads();
    for (int o = 128; o > 0; o >>= 1) {
        if (t < o) lds[t] += lds[t + o];
        __syncthreads();
    }
    if (t == 0) bsum[lb] = lds[0];
}

__global__ __launch_bounds__(512) void scan_bsum2_kernel(int* __restrict__ bt,
    int* __restrict__ bu)
{
    __shared__ int lds[512];
    int t = threadIdx.x;
    {
        int v = (t < NB_T) ? bt[t] : 0;
        lds[t] = v;
        __syncthreads();
        for (int o = 1; o < 512; o <<= 1) {
            int x = (t >= o) ? lds[t - o] : 0;
            __syncthreads();
            lds[t] += x;
            __syncthreads();
        }
        if (t < NB_T) bt[t] = lds[t] - v;
        __syncthreads();
    }
    {
        int v = (t < NB_U) ? bu[t] : 0;
        lds[t] = v;
        __syncthreads();
        for (int o = 1; o < 512; o <<= 1) {
            int x = (t >= o) ? lds[t - o] : 0;
            __syncthreads();
            lds[t] += x;
            __syncthreads();
        }
        if (t < NB_U) bu[t] = lds[t] - v;
    }
}

__global__ __launch_bounds__(256) void scan_final2_kernel(
    const int* __restrict__ deg_t, const int* __restrict__ be_t,
    int* __restrict__ rowptr_t, int* __restrict__ cur_t,
    const int* __restrict__ deg_u, const int* __restrict__ be_u,
    int* __restrict__ rowptr_u, int* __restrict__ cur_u)
{
    __shared__ int lds[256];
    int b = blockIdx.x, t = threadIdx.x;
    const int* deg; const int* be; int* rowptr; int* cursor; int Nd, lb;
    if (b < NB_T) { deg = deg_t; be = be_t; rowptr = rowptr_t; cursor = cur_t; Nd = N_TX; lb = b; }
    else         { deg = deg_u; be = be_u; rowptr = rowptr_u; cursor = cur_u; Nd = N_USER; lb = b - NB_T; }
    int i = lb * 256 + t;
    int v = (i < Nd) ? deg[i] : 0;
    lds[t] = v;
    __syncthreads();
    for (int o = 1; o < 256; o <<= 1) {
        int x = (t >= o) ? lds[t - o] : 0;
        __syncthreads();
        lds[t] += x;
        __syncthreads();
    }
    int excl = lds[t] - v + be[lb];
    if (i < Nd) {
        rowptr[i] = excl;
        cursor[i] = excl;
        if (i == Nd - 1) rowptr[Nd] = NE;
    }
}

__global__ __launch_bounds__(256) void scatter2_kernel(
    const int* __restrict__ src_t, const int* __restrict__ dst_t,
    int* __restrict__ cur_t, int* __restrict__ csr_t,
    const int* __restrict__ src_u, const int* __restrict__ dst_u,
    int* __restrict__ cur_u, int* __restrict__ csr_u)
{
    int e = blockIdx.x * 256 + threadIdx.x;
    if (e < NE) {
        int p = atomicAdd(&cur_t[dst_t[e]], 1);
        csr_t[p] = src_t[e];
    } else {
        e -= NE;
        if (e < NE) {
            int p = atomicAdd(&cur_u[dst_u[e]], 1);
            csr_u[p] = src_u[e];
        }
    }
}

// ================= conv1 aggregation: one wave per dst node (high occupancy) =================
__device__ __forceinline__ void acc_edge(int s, int lane,
    const float* __restrict__ als, const float* __restrict__ hsrc, const float4& A,
    float& a0, float& a1, float& a2, float& a3,
    float& w0, float& w1, float& w2, float& w3)
{
    float4 v = *(const float4*)(als + (size_t)s * 4);
    float x = hsrc[(size_t)s * 64 + lane];
    float e0 = lrelu_exp(v.x + A.x);
    float e1 = lrelu_exp(v.y + A.y);
    float e2 = lrelu_exp(v.z + A.z);
    float e3 = lrelu_exp(v.w + A.w);
    a0 = fmaf(e0, x, a0); w0 += e0;
    a1 = fmaf(e1, x, a1); w1 += e1;
    a2 = fmaf(e2, x, a2); w2 += e2;
    a3 = fmaf(e3, x, a3); w3 += e3;
}

__global__ __launch_bounds__(256) void agg_conv1_kernel(const int* __restrict__ rowptr,
    const int* __restrict__ csr, const float* __restrict__ hsrc,
    const float* __restrict__ als, const float* __restrict__ ald,
    float* __restrict__ agg, int Nd)
{
    int d = blockIdx.x * 4 + (threadIdx.x >> 6);
    int lane = threadIdx.x & 63;
    if (d >= Nd) return;
    int beg = rowptr[d], end = rowptr[d + 1];
    float4 A = *(const float4*)(ald + (size_t)d * 4);
    float a0 = 0.f, a1 = 0.f, a2 = 0.f, a3 = 0.f;
    float w0 = 0.f, w1 = 0.f, w2 = 0.f, w3 = 0.f;
    int i = beg;
    for (; i + 2 <= end; i += 2) {
        acc_edge(csr[i],     lane, als, hsrc, A, a0, a1, a2, a3, w0, w1, w2, w3);
        acc_edge(csr[i + 1], lane, als, hsrc, A, a0, a1, a2, a3, w0, w1, w2, w3);
    }
    if (i < end)
        acc_edge(csr[i], lane, als, hsrc, A, a0, a1, a2, a3, w0, w1, w2, w3);
    float* o = agg + (size_t)d * 256;
    o[lane]       = a0 / (w0 + 1e-16f);
    o[64 + lane]  = a1 / (w1 + 1e-16f);
    o[128 + lane] = a2 / (w2 + 1e-16f);
    o[192 + lane] = a3 / (w3 + 1e-16f);
}

// ================= conv1 dst-side transform v3: W in VGPRs, x via LDS broadcast ============
// TN nodes per block (TN*1KB LDS). Wave w = head h; lane j holds W1[:, h*64+j] in VGPRs.
template<int TN>
__global__ __launch_bounds__(256, 4) void transform_v3(
    const float* __restrict__ agg, const float* __restrict__ W1,
    const float* __restrict__ b1, const float* __restrict__ vvec,
    float* __restrict__ dot_part, float* __restrict__ rows_out,
    int Nd, int writeRows)
{
    __shared__ float sX[TN * 256];      // node-major
    const int tid = threadIdx.x;
    const int lane = tid & 63;
    const int w = tid >> 6;
    const int base = blockIdx.x * TN;

    // stage: coalesced float4 loads, each wave stages TN/4 rows
    #pragma unroll
    for (int it = 0; it < TN / 4; ++it) {
        int rl = w * (TN / 4) + it, gr = base + rl;
        float4 v = make_float4(0.f, 0.f, 0.f, 0.f);
        if (gr < Nd) v = *(const float4*)(agg + (size_t)gr * 256 + lane * 4);
        *(float4*)(sX + rl * 256 + lane * 4) = v;
    }

    // W column into registers (once per block, coalesced)
    float Wreg[64];
    #pragma unroll
    for (int c = 0; c < 64; ++c)
        Wreg[c] = W1[(size_t)c * 256 + w * 64 + lane];
    const float breg = b1[w * 64 + lane];
    const float vreg = vvec[w * 64 + lane];
    __syncthreads();

    float* dp = dot_part + (size_t)w * Nd;

    for (int nn = 0; nn < TN; nn += 2) {
        const float* x0 = sX + nn * 256 + w * 64;
        const float* x1 = x0 + 256;
        float a0 = breg, c0 = 0.f, a1 = breg, c1 = 0.f;   // 4 independent chains
        #pragma unroll
        for (int c = 0; c < 64; c += 8) {
            float4 p0 = *(const float4*)(x0 + c);
            float4 q0 = *(const float4*)(x0 + c + 4);
            float4 p1 = *(const float4*)(x1 + c);
            float4 q1 = *(const float4*)(x1 + c + 4);
            a0 = fmaf(p0.x, Wreg[c],     a0); c0 = fmaf(p0.y, Wreg[c + 1], c0);
            a0 = fmaf(p0.z, Wreg[c + 2], a0); c0 = fmaf(p0.w, Wreg[c + 3], c0);
            a0 = fmaf(q0.x, Wreg[c + 4], a0); c0 = fmaf(q0.y, Wreg[c + 5], c0);
            a0 = fmaf(q0.z, Wreg[c + 6], a0); c0 = fmaf(q0.w, Wreg[c + 7], c0);
            a1 = fmaf(p1.x, Wreg[c],     a1); c1 = fmaf(p1.y, Wreg[c + 1], c1);
            a1 = fmaf(p1.z, Wreg[c + 2], a1); c1 = fmaf(p1.w, Wreg[c + 3], c1);
            a1 = fmaf(q1.x, Wreg[c + 4], a1); c1 = fmaf(q1.y, Wreg[c + 5], c1);
            a1 = fmaf(q1.z, Wreg[c + 6], a1); c1 = fmaf(q1.w, Wreg[c + 7], c1);
        }
        float v0 = a0 + c0; v0 = v0 > 0.f ? v0 : (expf(v0) - 1.f);
        float v1 = a1 + c1; v1 = v1 > 0.f ? v1 : (expf(v1) - 1.f);
        int g0 = base + nn, g1 = g0 + 1;
        if (writeRows) {
            if (g0 < Nd) rows_out[(size_t)g0 * 256 + w * 64 + lane] = v0;
            if (g1 < Nd) rows_out[(size_t)g1 * 256 + w * 64 + lane] = v1;
        }
        float s0 = v0 * vreg, s1 = v1 * vreg;
        #pragma unroll
        for (int off = 32; off > 0; off >>= 1) {
            s0 += __shfl_down(s0, off);
            s1 += __shfl_down(s1, off);
        }
        if (lane == 0) {
            if (g0 < Nd) dp[g0] = s0;
            if (g1 < Nd) dp[g1] = s1;
        }
    }
}

// ------------- sum 4 head partials: o1[i] = sum_h ap[h*N1+i]; o2 likewise -------------
__global__ __launch_bounds__(256) void combine_parts(
    const float* __restrict__ ap, float* __restrict__ o1, int N1,
    const float* __restrict__ bp, float* __restrict__ o2, int N2)
{
    int i = blockIdx.x * 256 + threadIdx.x;
    if (i < N1) {
        o1[i] = ap[i] + ap[N1 + i] + ap[2 * N1 + i] + ap[3 * N1 + i];
    } else {
        int j = i - N1;
        if (j < N2)
            o2[j] = bp[j] + bp[N2 + j] + bp[2 * N2 + j] + bp[3 * N2 + j];
    }
}

// ================= conv2: fused edge-softmax + aggregation + bias/ELU + classifier ==========
__global__ __launch_bounds__(256) void conv2_fused_kernel(const int* __restrict__ rowptr,
    const int* __restrict__ csr, const float* __restrict__ hs2,
    const float* __restrict__ als2, const float* __restrict__ ald2,
    const float* __restrict__ b2, const float* __restrict__ Wc, const float* __restrict__ bc,
    float* __restrict__ out, int Nd)
{
    int d = blockIdx.x * 4 + (threadIdx.x >> 6);
    int lane = threadIdx.x & 63;
    if (d >= Nd) return;
    int beg = rowptr[d], end = rowptr[d + 1];
    float aldd = ald2[d];
    int half = lane >> 5, c = lane & 31;
    float acc = 0.f, wsum = 0.f;
    for (int i = beg + half; i < end; i += 2) {
        int s = csr[i];
        float w = lrelu_exp(als2[s] + aldd);
        acc = fmaf(w, hs2[(size_t)s * 32 + c], acc);
        wsum += w;
    }
    acc  += __shfl_down(acc, 32);
    wsum += __shfl_down(wsum, 32);
    float val = 0.f;
    if (lane < 32) {
        float t2 = acc / (wsum + 1e-16f) + b2[c];
        t2 = t2 > 0.f ? t2 : (expf(t2) - 1.f);
        val = t2 * Wc[c];
    }
    #pragma unroll
    for (int o = 16; o > 0; o >>= 1) val += __shfl_down(val, o);
    if (lane == 0) out[d] = val + bc[0];
}

extern "C" void kernel_launch(void* const* d_in, const int* in_sizes, int n_in,
                              void* d_out, int out_size, void* d_ws, size_t ws_size,
                              hipStream_t stream)
{
    const float* x_tx    = (const float*)d_in[0];
    const float* x_user  = (const float*)d_in[1];
    const int*   ei_u2t  = (const int*)d_in[2];
    const int*   ei_t2u  = (const int*)d_in[3];
    const float* Wp_tx   = (const float*)d_in[4];
    const float* bp_tx   = (const float*)d_in[5];
    const float* Wp_user = (const float*)d_in[6];
    const float* bp_user = (const float*)d_in[7];
    const float* W1_u2t  = (const float*)d_in[8];
    const float* as1_u2t = (const float*)d_in[9];
    const float* ad1_u2t = (const float*)d_in[10];
    const float* b1_u2t  = (const float*)d_in[11];
    const float* W2_u2t  = (const float*)d_in[12];
    const float* as2_u2t = (const float*)d_in[13];
    const float* ad2_u2t = (const float*)d_in[14];
    const float* b2_u2t  = (const float*)d_in[15];
    const float* W1_t2u  = (const float*)d_in[16];
    const float* as1_t2u = (const float*)d_in[17];
    const float* ad1_t2u = (const float*)d_in[18];
    const float* b1_t2u  = (const float*)d_in[19];
    const float* Wc      = (const float*)d_in[24];
    const float* bc      = (const float*)d_in[25];
    float* out = (float*)d_out;
    float* ws  = (float*)d_ws;

    const int* src_u2t = ei_u2t;            // user ids
    const int* dst_u2t = ei_u2t + NE;       // tx ids
    const int* src_t2u = ei_t2u;            // tx ids
    const int* dst_u   = ei_t2u + NE;       // user ids

    // ---- workspace layout (floats) ----
    float* h_tx   = ws;                     //  6,400,000
    float* h_us   = ws + 6400000;           //  3,200,000
    float* hs2    = ws + 9600000;           //  1,600,000  (ald2p/als2p alias here pre-gemm)
    float* als2   = ws + 11200000;          //     50,000
    float* ald2   = ws + 11250000;          //    100,000
    float* als_us = ws + 11350000;          //    200,000  (user src-attn for u2t)
    float* ald_us = ws + 11550000;          //    200,000  (user dst-attn for t2u)
    float* als_tx = ws + 11750000;          //    400,000  (tx src-attn for t2u)
    float* ald_tx = ws + 12150000;          //    400,000  (tx dst-attn for u2t)
    float* agg    = ws + 12550000;          // 25,600,000  (u2t then t2u; u1 in place)
    float* avec   = ws + 38150000;          //      1,536
    float* ald2p = hs2;                     //    400,000  (4 x N_TX, aliases hs2)
    float* als2p = hs2 + 400000;            //    200,000  (4 x N_USER)
    // ---- int region ----
    int* ibase    = (int*)(ws + 38152000);
    int* deg_t    = ibase;                  //   100,000
    int* deg_u    = ibase + 100000;         //    50,000
    int* rowptr_t = ibase + 150000;         //   100,001
    int* cur_t    = ibase + 250001;         //   100,000
    int* csr_t    = ibase + 350001;         //   500,000
    int* rowptr_u = ibase + 850001;         //    50,001
    int* cur_u    = ibase + 900002;         //    50,000
    int* csr_u    = ibase + 950002;         //   500,000
    int* bsum_t   = ibase + 1450002;        //       512
    int* bsum_u   = ibase + 1450514;        //       512

    float* Msrc_u2t = avec + 0;
    float* Mdst_u2t = avec + 256;
    float* Msrc_t2u = avec + 512;
    float* Mdst_t2u = avec + 768;
    float* vsrc2    = avec + 1024;          // fold(W2, as2): als2 = u1 . vsrc2
    float* vdst2    = avec + 1280;          // fold(W2, ad2): ald2 = t1 . vdst2

    // ---- fold attention vectors into weights ----
    AVArgs6 av;
    av.t[0] = { W1_u2t, as1_u2t, Msrc_u2t, HID, NH, HID };
    av.t[1] = { W1_u2t, ad1_u2t, Mdst_u2t, HID, NH, HID };
    av.t[2] = { W1_t2u, as1_t2u, Msrc_t2u, HID, NH, HID };
    av.t[3] = { W1_t2u, ad1_t2u, Mdst_t2u, HID, NH, HID };
    av.t[4] = { W2_u2t, as2_u2t, vsrc2, HC1, 1, OUTC };
    av.t[5] = { W2_u2t, ad2_u2t, vdst2, HC1, 1, OUTC };
    attn_vecs_kernel<<<6, 256, 0, stream>>>(av);

    // ---- zero degree histograms ----
    hipMemsetAsync(deg_t, 0, 150000 * sizeof(int), stream);

    // ---- CSR build for both edge types (5 launches) ----
    hist2_kernel<<<(2 * NE + 255) / 256, 256, 0, stream>>>(dst_u2t, dst_u, deg_t, deg_u);
    block_sum2_kernel<<<NB_T + NB_U, 256, 0, stream>>>(deg_t, bsum_t, deg_u, bsum_u);
    scan_bsum2_kernel<<<1, 512, 0, stream>>>(bsum_t, bsum_u);
    scan_final2_kernel<<<NB_T + NB_U, 256, 0, stream>>>(
        deg_t, bsum_t, rowptr_t, cur_t, deg_u, bsum_u, rowptr_u, cur_u);
    scatter2_kernel<<<(2 * NE + 255) / 256, 256, 0, stream>>>(
        src_u2t, dst_u2t, cur_t, csr_t, src_t2u, dst_u, cur_u, csr_u);

    // ---- input projections ----
    gemm_kernel<<<dim3(1, (N_TX + 63) / 64), 256, 0, stream>>>(
        x_tx, Wp_tx, bp_tx, h_tx, N_TX, F_TX, HID, 1);
    gemm_kernel<<<dim3(1, (N_USER + 63) / 64), 256, 0, stream>>>(
        x_user, Wp_user, bp_user, h_us, N_USER, F_USER, HID, 1);

    // ---- node attention scalars (both node types, one launch) ----
    node_attn8_dual<<<(N_TX + N_USER) / 4, 256, 0, stream>>>(
        h_tx, Mdst_u2t, Msrc_t2u, ald_tx, als_tx,
        h_us, Msrc_u2t, Mdst_t2u, als_us, ald_us);

    // ================= conv1, u2t (dst = tx): agg -> transform -> ald2 partials ==========
    agg_conv1_kernel<<<(N_TX + 3) / 4, 256, 0, stream>>>(
        rowptr_t, csr_t, h_us, als_us, ald_tx, agg, N_TX);
    transform_v3<32><<<(N_TX + 31) / 32, 256, 0, stream>>>(
        agg, W1_u2t, b1_u2t, vdst2, ald2p, nullptr, N_TX, 0);

    // ================= conv1, t2u (dst = user): agg -> transform (u1 in place) ==========
    agg_conv1_kernel<<<(N_USER + 3) / 4, 256, 0, stream>>>(
        rowptr_u, csr_u, h_tx, als_tx, ald_us, agg, N_USER);
    transform_v3<32><<<(N_USER + 31) / 32, 256, 0, stream>>>(
        agg, W1_t2u, b1_t2u, vsrc2, als2p, agg, N_USER, 1);
    float* u1 = agg;

    // ---- combine head partials ----
    combine_parts<<<(N_TX + N_USER + 255) / 256, 256, 0, stream>>>(
        ald2p, ald2, N_TX, als2p, als2, N_USER);

    // ================= conv2 projection + fused conv2/classifier =================
    gemm_kernel<<<dim3(1, (N_USER + 63) / 64), 256, 0, stream>>>(
        u1, W2_u2t, nullptr, hs2, N_USER, HC1, OUTC, 0);
    conv2_fused_kernel<<<(N_TX + 3) / 4, 256, 0, stream>>>(
        rowptr_t, csr_t, hs2, als2, ald2, b2_u2t, Wc, bc, out, N_TX);
}